// Round 1
// baseline (1676.524 us; speedup 1.0000x reference)
//
#include <hip/hip_runtime.h>
#include <hip/hip_bf16.h>
#include <math.h>

// HGNN forward, MI355X.
// Structure: deg/dinv -> input proj (fused with self-loop init of agg0/agg1)
//            -> scatter e0 into agg0, e1 into agg1
//            -> s1 = max(agg0@W0+b0, agg1@W1+b1), init agg0s1 = s1*dinv0^2
//            -> scatter e0 (input s1) into agg0s1
//            -> s2 = max(agg0@W2+b2, agg0s1@W3c+b3c); LN; gelu; @W3+b3 -> out
// attn == softmax over size-1 axis == 1.0 exactly, so W1/b1/W2/b2 are unused.

#define HID 64

__global__ void count_deg(const int* __restrict__ dst0, const int* __restrict__ dst1,
                          int E, int* __restrict__ deg0, int* __restrict__ deg1) {
    int i = blockIdx.x * blockDim.x + threadIdx.x;
    int stride = gridDim.x * blockDim.x;
    for (; i < E; i += stride) {
        atomicAdd(&deg0[dst0[i]], 1);
        atomicAdd(&deg1[dst1[i]], 1);
    }
}

// buffer holds int counts; rewrite in place as float rsqrt(count+1)
__global__ void finalize_dinv(float* __restrict__ d, int n) {
    int i = blockIdx.x * blockDim.x + threadIdx.x;
    if (i < n) {
        int cnt = reinterpret_cast<int*>(d)[i];
        d[i] = rsqrtf((float)(cnt + 1));
    }
}

// hid = x @ W_in[type] + b_in[type];  t0 = hid*dinv0^2;  t1 = hid*dinv1^2
__global__ void input_proj(const float* __restrict__ x, const int* __restrict__ types,
                           const float* __restrict__ W_in, const float* __restrict__ b_in,
                           const float* __restrict__ dinv0, const float* __restrict__ dinv1,
                           float* __restrict__ hid, float* __restrict__ t0, float* __restrict__ t1,
                           int N, int F) {
    __shared__ float xs[4 * 128];   // F == 128
    int tid = threadIdx.x;
    int w = tid >> 6, h = tid & 63;
    int n0 = blockIdx.x * 4;
    for (int i = tid; i < 4 * F; i += 256) {
        int nn = n0 + i / F;
        xs[i] = (nn < N) ? x[(size_t)nn * F + (i % F)] : 0.0f;
    }
    __syncthreads();
    int n = n0 + w;
    if (n >= N) return;
    int t = types[n];
    const float* W = W_in + (size_t)t * F * HID;
    float acc = b_in[t * HID + h];
    const float* xr = xs + w * F;
    #pragma unroll 4
    for (int f = 0; f < F; ++f)
        acc = fmaf(xr[f], W[(size_t)f * HID + h], acc);
    size_t idx = (size_t)n * HID + h;
    hid[idx] = acc;
    float d0 = dinv0[n], d1 = dinv1[n];
    t0[idx] = acc * d0 * d0;
    t1[idx] = acc * d1 * d1;
}

// one wave per edge; lane = feature; out[dst] += xin[src] * dinv[src]*dinv[dst]
__global__ void scatter_add(const int* __restrict__ src, const int* __restrict__ dst,
                            const float* __restrict__ dinv, const float* __restrict__ xin,
                            float* __restrict__ out, int E) {
    int wid = (blockIdx.x * blockDim.x + threadIdx.x) >> 6;
    int lane = threadIdx.x & 63;
    int nw = (gridDim.x * blockDim.x) >> 6;
    for (int e = wid; e < E; e += nw) {
        int s = src[e], d = dst[e];
        float norm = dinv[s] * dinv[d];
        atomicAdd(&out[(size_t)d * HID + lane], xin[(size_t)s * HID + lane] * norm);
    }
}

// s1 = max(t0@W0+b0, t1@W1+b1) -> write into t1; t2 = s1*dinv0^2
__global__ void combine_s1(const float* __restrict__ t0, float* __restrict__ t1,
                           const float* __restrict__ W_conv, const float* __restrict__ b_conv,
                           const float* __restrict__ dinv0, float* __restrict__ t2, int N) {
    int w = threadIdx.x >> 6, h = threadIdx.x & 63;
    int n = blockIdx.x * 4 + w;
    if (n >= N) return;
    const float* a0 = t0 + (size_t)n * HID;
    const float* a1 = t1 + (size_t)n * HID;
    const float* W0 = W_conv;
    const float* W1 = W_conv + HID * HID;
    float acc0 = b_conv[0 * HID + h];
    float acc1 = b_conv[1 * HID + h];
    #pragma unroll 8
    for (int k = 0; k < HID; ++k) {
        acc0 = fmaf(a0[k], W0[k * HID + h], acc0);
        acc1 = fmaf(a1[k], W1[k * HID + h], acc1);
    }
    float s1 = fmaxf(acc0, acc1);
    size_t idx = (size_t)n * HID + h;
    t1[idx] = s1;                     // safe: whole wave's loads precede the store
    float d0 = dinv0[n];
    t2[idx] = s1 * d0 * d0;
}

// s2 = max(t0@W2+b2, t2@W3c+b3c); LayerNorm; exact gelu; out = g@W3 + b3
__global__ void finalize_out(const float* __restrict__ t0, const float* __restrict__ t2,
                             const float* __restrict__ W_conv, const float* __restrict__ b_conv,
                             const float* __restrict__ W3, const float* __restrict__ b3,
                             float* __restrict__ out, int N) {
    int w = threadIdx.x >> 6, h = threadIdx.x & 63;
    int n = blockIdx.x * 4 + w;
    __shared__ float gs[4][HID];
    bool valid = (n < N);
    if (valid) {
        const float* a2 = t0 + (size_t)n * HID;
        const float* a3 = t2 + (size_t)n * HID;
        const float* W2 = W_conv + 2 * HID * HID;
        const float* W3c = W_conv + 3 * HID * HID;
        float acc2 = b_conv[2 * HID + h];
        float acc3 = b_conv[3 * HID + h];
        #pragma unroll 8
        for (int k = 0; k < HID; ++k) {
            acc2 = fmaf(a2[k], W2[k * HID + h], acc2);
            acc3 = fmaf(a3[k], W3c[k * HID + h], acc3);
        }
        float s2 = fmaxf(acc2, acc3);
        // LayerNorm over the 64 lanes
        float sum = s2;
        #pragma unroll
        for (int off = 32; off; off >>= 1) sum += __shfl_xor(sum, off, 64);
        float mu = sum * (1.0f / 64.0f);
        float dv = s2 - mu;
        float v = dv * dv;
        #pragma unroll
        for (int off = 32; off; off >>= 1) v += __shfl_xor(v, off, 64);
        float xn = dv * rsqrtf(v * (1.0f / 64.0f) + 1e-5f);
        float g = 0.5f * xn * (1.0f + erff(xn * 0.70710678118654752f));
        gs[w][h] = g;
    }
    __syncthreads();
    if (valid && h < 8) {
        float acc = b3[h];
        #pragma unroll 8
        for (int k = 0; k < HID; ++k)
            acc = fmaf(gs[w][k], W3[k * 8 + h], acc);
        out[(size_t)n * 8 + h] = acc;
    }
}

extern "C" void kernel_launch(void* const* d_in, const int* in_sizes, int n_in,
                              void* d_out, int out_size, void* d_ws, size_t ws_size,
                              hipStream_t stream) {
    const float* x          = (const float*)d_in[0];
    const int*   node_types = (const int*)d_in[1];
    const int*   e0         = (const int*)d_in[2];   // (2,E): [0..E)=src, [E..2E)=dst
    const int*   e1         = (const int*)d_in[3];
    const float* W_in       = (const float*)d_in[4];
    const float* b_in       = (const float*)d_in[5];
    const float* W_conv     = (const float*)d_in[6];
    const float* b_conv     = (const float*)d_in[7];
    // d_in[8..11] (W1,b1,W2,b2) unused: softmax over size-1 axis == 1
    const float* W3         = (const float*)d_in[12];
    const float* b3         = (const float*)d_in[13];
    float* out = (float*)d_out;

    int N = in_sizes[1];
    int F = in_sizes[0] / N;    // 128
    int E = in_sizes[2] / 2;    // 1.6M

    float* ws    = (float*)d_ws;
    float* dinv0 = ws;                       // N
    float* dinv1 = ws + N;                   // N
    float* hid   = ws + 2 * (size_t)N;       // 64N  (reused as t2 later)
    float* t0    = hid + (size_t)64 * N;     // 64N
    float* t1    = t0 + (size_t)64 * N;      // 64N
    float* t2    = hid;                      // alias: hid dead after scatters

    hipMemsetAsync(dinv0, 0, 2 * (size_t)N * sizeof(float), stream);
    count_deg<<<1024, 256, 0, stream>>>(e0 + E, e1 + E, E, (int*)dinv0, (int*)dinv1);
    finalize_dinv<<<(2 * N + 255) / 256, 256, 0, stream>>>(ws, 2 * N);
    input_proj<<<(N + 3) / 4, 256, 0, stream>>>(x, node_types, W_in, b_in,
                                                dinv0, dinv1, hid, t0, t1, N, F);
    scatter_add<<<2048, 256, 0, stream>>>(e0, e0 + E, dinv0, hid, t0, E);
    scatter_add<<<2048, 256, 0, stream>>>(e1, e1 + E, dinv1, hid, t1, E);
    combine_s1<<<(N + 3) / 4, 256, 0, stream>>>(t0, t1, W_conv, b_conv, dinv0, t2, N);
    scatter_add<<<2048, 256, 0, stream>>>(e0, e0 + E, dinv0, t1, t2, E);
    finalize_out<<<(N + 3) / 4, 256, 0, stream>>>(t0, t2, W_conv, b_conv, W3, b3, out, N);
}

// Round 2
// 909.590 us; speedup vs baseline: 1.8432x; 1.8432x over previous
//
#include <hip/hip_runtime.h>
#include <hip/hip_bf16.h>
#include <math.h>

// HGNN forward, MI355X — round 2: CSR-gather instead of atomic scatter.
// Pipeline:
//   memset(deg) -> count_deg -> make_dinv -> scan(off0) -> scan(off1)
//   -> fill_csr (atomicSub on deg as cursor; segment order irrelevant)
//   -> input_proj (hid = x @ W_in[type] + b_in[type])
//   -> layer1: per-node gather over csr0 & csr1 of hid (+self loop),
//              matvec W0/W1 (wave-local LDS), s1 = max  [also stores agg0=t0]
//   -> layer2: per-node gather over csr0 of s1 (+self), matvec W2 on t0,
//              W3c on agg, max, LayerNorm, exact gelu, @W3+b3 -> out
// attn == softmax over size-1 axis == 1.0 exactly, so W1/b1/W2/b2 are unused.

#define HID 64

// ---------------- degree count ----------------
__global__ void count_deg(const int* __restrict__ dst0, const int* __restrict__ dst1,
                          int E, int* __restrict__ deg0, int* __restrict__ deg1) {
    int i = blockIdx.x * blockDim.x + threadIdx.x;
    int stride = gridDim.x * blockDim.x;
    for (; i < E; i += stride) {
        atomicAdd(&deg0[dst0[i]], 1);
        atomicAdd(&deg1[dst1[i]], 1);
    }
}

__global__ void make_dinv(const int* __restrict__ deg, float* __restrict__ dinv, int n2) {
    int i = blockIdx.x * blockDim.x + threadIdx.x;
    if (i < n2) dinv[i] = rsqrtf((float)(deg[i] + 1));   // +1 self loop
}

// ---------------- exclusive scan (1024 elems / block) ----------------
__global__ void scan_local(const int* __restrict__ deg, int* __restrict__ off,
                           int* __restrict__ bsums, int n) {
    __shared__ int tmp[256];
    int tid = threadIdx.x;
    int idx0 = blockIdx.x * 1024 + tid * 4;
    int v0 = (idx0 + 0 < n) ? deg[idx0 + 0] : 0;
    int v1 = (idx0 + 1 < n) ? deg[idx0 + 1] : 0;
    int v2 = (idx0 + 2 < n) ? deg[idx0 + 2] : 0;
    int v3 = (idx0 + 3 < n) ? deg[idx0 + 3] : 0;
    int s = v0 + v1 + v2 + v3;
    tmp[tid] = s;
    __syncthreads();
    for (int o = 1; o < 256; o <<= 1) {
        int t = (tid >= o) ? tmp[tid - o] : 0;
        __syncthreads();
        tmp[tid] += t;
        __syncthreads();
    }
    int excl = tmp[tid] - s;
    if (tid == 255) bsums[blockIdx.x] = tmp[255];
    if (idx0 + 0 < n) off[idx0 + 0] = excl;
    if (idx0 + 1 < n) off[idx0 + 1] = excl + v0;
    if (idx0 + 2 < n) off[idx0 + 2] = excl + v0 + v1;
    if (idx0 + 3 < n) off[idx0 + 3] = excl + v0 + v1 + v2;
}

__global__ void scan_bsums(int* __restrict__ bsums, int nb) {
    if (threadIdx.x == 0 && blockIdx.x == 0) {
        int acc = 0;
        for (int i = 0; i < nb; ++i) { int t = bsums[i]; bsums[i] = acc; acc += t; }
    }
}

__global__ void scan_add(int* __restrict__ off, const int* __restrict__ bsums,
                         const int* __restrict__ deg, int n) {
    int i = blockIdx.x * blockDim.x + threadIdx.x;
    if (i < n) {
        int v = off[i] + bsums[i >> 10];
        off[i] = v;
        if (i == n - 1) off[n] = v + deg[i];
    }
}

// ---------------- CSR fill (destroys deg as reverse cursor) ----------------
__global__ void fill_csr(const int* __restrict__ src0, const int* __restrict__ dst0,
                         const int* __restrict__ off0, int* __restrict__ deg0,
                         int* __restrict__ csr0,
                         const int* __restrict__ src1, const int* __restrict__ dst1,
                         const int* __restrict__ off1, int* __restrict__ deg1,
                         int* __restrict__ csr1, int E) {
    int i = blockIdx.x * blockDim.x + threadIdx.x;
    int stride = gridDim.x * blockDim.x;
    for (; i < E; i += stride) {
        int s = src0[i], d = dst0[i];
        int pos = off0[d] + atomicSub(&deg0[d], 1) - 1;
        csr0[pos] = s;
        s = src1[i]; d = dst1[i];
        pos = off1[d] + atomicSub(&deg1[d], 1) - 1;
        csr1[pos] = s;
    }
}

// ---------------- input projection ----------------
__global__ void input_proj(const float* __restrict__ x, const int* __restrict__ types,
                           const float* __restrict__ W_in, const float* __restrict__ b_in,
                           float* __restrict__ hid, int N, int F) {
    __shared__ float xs[4 * 128];   // F == 128
    int tid = threadIdx.x;
    int w = tid >> 6, h = tid & 63;
    int n0 = blockIdx.x * 4;
    for (int i = tid; i < 4 * F; i += 256) {
        int nn = n0 + i / F;
        xs[i] = (nn < N) ? x[(size_t)nn * F + (i % F)] : 0.0f;
    }
    __syncthreads();
    int n = n0 + w;
    if (n >= N) return;
    int t = types[n];
    const float* W = W_in + (size_t)t * F * HID;
    float acc = b_in[t * HID + h];
    const float* xr = xs + w * F;
    #pragma unroll 4
    for (int f = 0; f < F; ++f)
        acc = fmaf(xr[f], W[(size_t)f * HID + h], acc);
    hid[(size_t)n * HID + h] = acc;
}

// ---------------- layer 1: two gathers + W0/W1 matvec + max ----------------
__global__ void layer1(const float* __restrict__ hid,
                       const int* __restrict__ off0, const int* __restrict__ csr0,
                       const float* __restrict__ dinv0,
                       const int* __restrict__ off1, const int* __restrict__ csr1,
                       const float* __restrict__ dinv1,
                       const float* __restrict__ W_conv, const float* __restrict__ b_conv,
                       float* __restrict__ t0, float* __restrict__ s1out, int N) {
    __shared__ float l0[4][HID], l1[4][HID];
    int w = threadIdx.x >> 6, h = threadIdx.x & 63;
    int n = blockIdx.x * 4 + w;
    if (n >= N) return;
    float d0 = dinv0[n], d1 = dinv1[n];
    float self = hid[(size_t)n * HID + h];
    float acc0 = self * d0 * d0;
    float acc1 = self * d1 * d1;
    // gather over edge list 0
    {
        int e = off0[n], e_ = off0[n + 1];
        for (; e + 3 < e_; e += 4) {
            int a = csr0[e], b = csr0[e + 1], c = csr0[e + 2], d = csr0[e + 3];
            float wa = dinv0[a] * d0, wb = dinv0[b] * d0, wc = dinv0[c] * d0, wd = dinv0[d] * d0;
            acc0 += hid[(size_t)a * HID + h] * wa;
            acc0 += hid[(size_t)b * HID + h] * wb;
            acc0 += hid[(size_t)c * HID + h] * wc;
            acc0 += hid[(size_t)d * HID + h] * wd;
        }
        for (; e < e_; ++e) {
            int a = csr0[e];
            acc0 += hid[(size_t)a * HID + h] * (dinv0[a] * d0);
        }
    }
    // gather over edge list 1
    {
        int e = off1[n], e_ = off1[n + 1];
        for (; e + 3 < e_; e += 4) {
            int a = csr1[e], b = csr1[e + 1], c = csr1[e + 2], d = csr1[e + 3];
            float wa = dinv1[a] * d1, wb = dinv1[b] * d1, wc = dinv1[c] * d1, wd = dinv1[d] * d1;
            acc1 += hid[(size_t)a * HID + h] * wa;
            acc1 += hid[(size_t)b * HID + h] * wb;
            acc1 += hid[(size_t)c * HID + h] * wc;
            acc1 += hid[(size_t)d * HID + h] * wd;
        }
        for (; e < e_; ++e) {
            int a = csr1[e];
            acc1 += hid[(size_t)a * HID + h] * (dinv1[a] * d1);
        }
    }
    t0[(size_t)n * HID + h] = acc0;     // agg0 reused by layer 2
    // matvecs (wave-local LDS — no block barrier needed)
    l0[w][h] = acc0;
    l1[w][h] = acc1;
    const float* W0 = W_conv;
    const float* W1 = W_conv + HID * HID;
    float m0 = b_conv[h];
    float m1 = b_conv[HID + h];
    #pragma unroll 8
    for (int k = 0; k < HID; ++k) {
        m0 = fmaf(l0[w][k], W0[k * HID + h], m0);
        m1 = fmaf(l1[w][k], W1[k * HID + h], m1);
    }
    s1out[(size_t)n * HID + h] = fmaxf(m0, m1);
}

// ------- layer 2: gather(s1 over csr0) + W2/W3c matvec + max + LN + gelu + W3 -------
__global__ void layer2(const float* __restrict__ t0, const float* __restrict__ s1in,
                       const int* __restrict__ off0, const int* __restrict__ csr0,
                       const float* __restrict__ dinv0,
                       const float* __restrict__ W_conv, const float* __restrict__ b_conv,
                       const float* __restrict__ W3, const float* __restrict__ b3,
                       float* __restrict__ out, int N) {
    __shared__ float l2[4][HID], l3[4][HID], gs[4][HID];
    int w = threadIdx.x >> 6, h = threadIdx.x & 63;
    int n = blockIdx.x * 4 + w;
    if (n >= N) return;
    float d0 = dinv0[n];
    float selfv = s1in[(size_t)n * HID + h];
    float acc = selfv * d0 * d0;
    {
        int e = off0[n], e_ = off0[n + 1];
        for (; e + 3 < e_; e += 4) {
            int a = csr0[e], b = csr0[e + 1], c = csr0[e + 2], d = csr0[e + 3];
            float wa = dinv0[a] * d0, wb = dinv0[b] * d0, wc = dinv0[c] * d0, wd = dinv0[d] * d0;
            acc += s1in[(size_t)a * HID + h] * wa;
            acc += s1in[(size_t)b * HID + h] * wb;
            acc += s1in[(size_t)c * HID + h] * wc;
            acc += s1in[(size_t)d * HID + h] * wd;
        }
        for (; e < e_; ++e) {
            int a = csr0[e];
            acc += s1in[(size_t)a * HID + h] * (dinv0[a] * d0);
        }
    }
    l3[w][h] = acc;
    l2[w][h] = t0[(size_t)n * HID + h];
    const float* W2  = W_conv + 2 * HID * HID;
    const float* W3c = W_conv + 3 * HID * HID;
    float m2 = b_conv[2 * HID + h];
    float m3 = b_conv[3 * HID + h];
    #pragma unroll 8
    for (int k = 0; k < HID; ++k) {
        m2 = fmaf(l2[w][k], W2[k * HID + h], m2);
        m3 = fmaf(l3[w][k], W3c[k * HID + h], m3);
    }
    float s2 = fmaxf(m2, m3);
    // LayerNorm over the 64 lanes
    float sum = s2;
    #pragma unroll
    for (int off = 32; off; off >>= 1) sum += __shfl_xor(sum, off, 64);
    float mu = sum * (1.0f / 64.0f);
    float dv = s2 - mu;
    float v = dv * dv;
    #pragma unroll
    for (int off = 32; off; off >>= 1) v += __shfl_xor(v, off, 64);
    float xn = dv * rsqrtf(v * (1.0f / 64.0f) + 1e-5f);
    float g = 0.5f * xn * (1.0f + erff(xn * 0.70710678118654752f));
    gs[w][h] = g;
    // wave-local: same wave wrote gs[w][*]
    if (h < 8) {
        float a = b3[h];
        #pragma unroll 8
        for (int k = 0; k < HID; ++k)
            a = fmaf(gs[w][k], W3[k * 8 + h], a);
        out[(size_t)n * 8 + h] = a;
    }
}

extern "C" void kernel_launch(void* const* d_in, const int* in_sizes, int n_in,
                              void* d_out, int out_size, void* d_ws, size_t ws_size,
                              hipStream_t stream) {
    const float* x          = (const float*)d_in[0];
    const int*   node_types = (const int*)d_in[1];
    const int*   e0         = (const int*)d_in[2];   // (2,E): [0..E)=src, [E..2E)=dst
    const int*   e1         = (const int*)d_in[3];
    const float* W_in       = (const float*)d_in[4];
    const float* b_in       = (const float*)d_in[5];
    const float* W_conv     = (const float*)d_in[6];
    const float* b_conv     = (const float*)d_in[7];
    const float* W3         = (const float*)d_in[12];
    const float* b3         = (const float*)d_in[13];
    float* out = (float*)d_out;

    int N = in_sizes[1];
    int F = in_sizes[0] / N;    // 128
    int E = in_sizes[2] / 2;    // 1.6M

    // workspace layout (4-byte units)
    int*   off0  = (int*)d_ws;                 // N+1
    int*   off1  = off0 + (N + 1);             // N+1
    int*   deg0  = off1 + (N + 1);             // N
    int*   deg1  = deg0 + N;                   // N
    int*   bsum0 = deg1 + N;                   // 256
    int*   bsum1 = bsum0 + 256;                // 256
    float* dinv0 = (float*)(bsum1 + 256);      // N
    float* dinv1 = dinv0 + N;                  // N
    int*   csr0  = (int*)(dinv1 + N);          // E
    int*   csr1  = csr0 + E;                   // E
    float* hid   = (float*)(csr1 + E);         // 64N
    float* t0    = hid + (size_t)HID * N;      // 64N
    float* s1    = t0 + (size_t)HID * N;       // 64N

    int nblk_scan = (N + 1023) / 1024;

    hipMemsetAsync(deg0, 0, 2 * (size_t)N * sizeof(int), stream);
    count_deg<<<2048, 256, 0, stream>>>(e0 + E, e1 + E, E, deg0, deg1);
    make_dinv<<<(2 * N + 255) / 256, 256, 0, stream>>>(deg0, dinv0, 2 * N);
    scan_local<<<nblk_scan, 256, 0, stream>>>(deg0, off0, bsum0, N);
    scan_local<<<nblk_scan, 256, 0, stream>>>(deg1, off1, bsum1, N);
    scan_bsums<<<1, 64, 0, stream>>>(bsum0, nblk_scan);
    scan_bsums<<<1, 64, 0, stream>>>(bsum1, nblk_scan);
    scan_add<<<(N + 255) / 256, 256, 0, stream>>>(off0, bsum0, deg0, N);
    scan_add<<<(N + 255) / 256, 256, 0, stream>>>(off1, bsum1, deg1, N);
    fill_csr<<<2048, 256, 0, stream>>>(e0, e0 + E, off0, deg0, csr0,
                                       e1, e1 + E, off1, deg1, csr1, E);
    input_proj<<<(N + 3) / 4, 256, 0, stream>>>(x, node_types, W_in, b_in, hid, N, F);
    layer1<<<(N + 3) / 4, 256, 0, stream>>>(hid, off0, csr0, dinv0, off1, csr1, dinv1,
                                            W_conv, b_conv, t0, s1, N);
    layer2<<<(N + 3) / 4, 256, 0, stream>>>(t0, s1, off0, csr0, dinv0,
                                            W_conv, b_conv, W3, b3, out, N);
}

// Round 4
// 635.205 us; speedup vs baseline: 2.6393x; 1.4320x over previous
//
#include <hip/hip_runtime.h>
#include <hip/hip_bf16.h>
#include <math.h>

// HGNN forward, MI355X — round 4: bucket-sorted CSR construction via
// deterministic block-level counting sort (no retry loops, LDS <= 34.5 KB).
// Pipeline:
//   memset(bcnt) -> histA -> scanA -> partB (chunked counting sort -> arena)
//   -> buildC (per-bucket LDS degree/scan/fill: off, dinv, csr)
//   -> input_proj -> layer1 (gathers+matvec+max) -> layer2 (+LN+gelu+W3)
// attn == softmax over size-1 axis == 1.0 exactly, so W1/b1/W2/b2 are unused.

#define HID   64
#define RB    128     // buckets per edge list
#define CHUNK 4096    // edges per block-chunk in partB

// ---------------- bucket histogram ----------------
__global__ void histA(const int* __restrict__ dst0, const int* __restrict__ dst1,
                      int E, int BW, int* __restrict__ bcnt) {
    __shared__ int h[2 * RB];
    for (int i = threadIdx.x; i < 2 * RB; i += blockDim.x) h[i] = 0;
    __syncthreads();
    int stride = gridDim.x * blockDim.x;
    for (int i = blockIdx.x * blockDim.x + threadIdx.x; i < E; i += stride) {
        atomicAdd(&h[dst0[i] / BW], 1);
        atomicAdd(&h[RB + dst1[i] / BW], 1);
    }
    __syncthreads();
    for (int i = threadIdx.x; i < 2 * RB; i += blockDim.x)
        if (h[i]) atomicAdd(&bcnt[i], h[i]);
}

// ---------------- bucket scan (256 elements, 1 block of 256) ----------------
__global__ void scanA(const int* __restrict__ bcnt, int* __restrict__ bbase,
                      int* __restrict__ bcur, int E,
                      int* __restrict__ off0, int* __restrict__ off1, int N) {
    __shared__ int t[2 * RB];
    int tid = threadIdx.x;             // 256 threads
    int orig = bcnt[tid];
    t[tid] = orig;
    __syncthreads();
    int list = tid >> 7, r = tid & (RB - 1);
    for (int o = 1; o < RB; o <<= 1) {
        int u = (r >= o) ? t[tid - o] : 0;
        __syncthreads();
        t[tid] += u;
        __syncthreads();
    }
    int incl = t[tid];
    int excl = incl - orig;
    bbase[list * (RB + 1) + r] = excl;
    bcur[tid] = excl;
    if (r == RB - 1) bbase[list * (RB + 1) + RB] = incl;   // == E
    if (tid == 0) { off0[N] = E; off1[N] = E; }
}

// ------- partition: chunked counting sort, (src,dst) -> bucket-ordered arena -------
__global__ void __launch_bounds__(256) partB(const int* __restrict__ e0,
                                             const int* __restrict__ e1,
                                             int E, int BW,
                                             int* __restrict__ bcur_all,
                                             uint2* __restrict__ arena_all) {
    __shared__ int hist[RB], scn[RB], lbase[RB], cur[RB], gbase[RB];
    __shared__ uint2 buf[CHUNK];                  // 32 KB
    int half = gridDim.x >> 1;
    int list = (blockIdx.x >= half) ? 1 : 0;
    const int* src = list ? e1 : e0;
    const int* dst = src + E;
    int* bcur = bcur_all + list * RB;
    uint2* arena = arena_all + (size_t)list * E;
    int blk = blockIdx.x - list * half;
    int tid = threadIdx.x;

    for (int c0 = blk * CHUNK; c0 < E; c0 += half * CHUNK) {
        int cn = min(CHUNK, E - c0);
        for (int i = tid; i < RB; i += 256) hist[i] = 0;
        __syncthreads();
        // pass A: count
        for (int i = tid; i < cn; i += 256)
            atomicAdd(&hist[dst[c0 + i] / BW], 1);
        __syncthreads();
        // scan hist -> exclusive lbase; reserve global space
        if (tid < RB) scn[tid] = hist[tid];
        __syncthreads();
        for (int o = 1; o < RB; o <<= 1) {
            int u = (tid < RB && tid >= o) ? scn[tid - o] : 0;
            __syncthreads();
            if (tid < RB) scn[tid] += u;
            __syncthreads();
        }
        if (tid < RB) {
            int ex = scn[tid] - hist[tid];
            lbase[tid] = ex;
            cur[tid]   = ex;
            gbase[tid] = hist[tid] ? atomicAdd(&bcur[tid], hist[tid]) : 0;
        }
        __syncthreads();
        // pass B: re-read, place bucket-grouped into LDS
        for (int i = tid; i < cn; i += 256) {
            int s = src[c0 + i], d = dst[c0 + i];
            int slot = atomicAdd(&cur[d / BW], 1);
            buf[slot] = make_uint2((unsigned)s, (unsigned)d);
        }
        __syncthreads();
        // pass C: write out (consecutive i in same bucket -> consecutive addrs)
        for (int i = tid; i < cn; i += 256) {
            uint2 p = buf[i];
            int b = (int)p.y / BW;
            arena[gbase[b] + (i - lbase[b])] = p;
        }
        __syncthreads();
    }
}

// ------- per-bucket CSR build: degree, scan, off, dinv, fill — all in LDS -------
__global__ void __launch_bounds__(1024) buildC(const uint2* __restrict__ arena_all,
                                               const int* __restrict__ bbase,
                                               int E, int N, int BW,
                                               int* __restrict__ csr0, int* __restrict__ csr1,
                                               int* __restrict__ off0, int* __restrict__ off1,
                                               float* __restrict__ dinv0, float* __restrict__ dinv1) {
    __shared__ int degl[800], scn[800], cur[800];
    int list = blockIdx.x >> 7, rb = blockIdx.x & (RB - 1);
    const uint2* arena = arena_all + (size_t)list * E;
    int* csr = list ? csr1 : csr0;
    int* off = list ? off1 : off0;
    float* dinv = list ? dinv1 : dinv0;
    int base = bbase[list * (RB + 1) + rb];
    int end  = bbase[list * (RB + 1) + rb + 1];
    int nbase = rb * BW;
    int nn = min(BW, N - nbase);
    if (nn <= 0) return;
    int tid = threadIdx.x;
    for (int i = tid; i < nn; i += 1024) degl[i] = 0;
    __syncthreads();
    for (int j = base + tid; j < end; j += 1024)
        atomicAdd(&degl[(int)arena[j].y - nbase], 1);
    __syncthreads();
    int v0 = (tid < nn) ? degl[tid] : 0;
    if (tid < nn) scn[tid] = v0;
    __syncthreads();
    for (int o = 1; o < nn; o <<= 1) {
        int u = (tid < nn && tid >= o) ? scn[tid - o] : 0;
        __syncthreads();
        if (tid < nn) scn[tid] += u;
        __syncthreads();
    }
    if (tid < nn) {
        int ex = scn[tid] - v0;                 // exclusive
        cur[tid] = ex;
        off[nbase + tid] = base + ex;
        dinv[nbase + tid] = rsqrtf((float)(v0 + 1));
    }
    __syncthreads();
    for (int j = base + tid; j < end; j += 1024) {
        uint2 p = arena[j];
        int loc = atomicAdd(&cur[(int)p.y - nbase], 1);
        csr[base + loc] = (int)p.x;
    }
}

// ---------------- input projection ----------------
__global__ void input_proj(const float* __restrict__ x, const int* __restrict__ types,
                           const float* __restrict__ W_in, const float* __restrict__ b_in,
                           float* __restrict__ hid, int N, int F) {
    __shared__ float xs[4 * 128];   // F == 128
    int tid = threadIdx.x;
    int w = tid >> 6, h = tid & 63;
    int n0 = blockIdx.x * 4;
    for (int i = tid; i < 4 * F; i += 256) {
        int nn = n0 + i / F;
        xs[i] = (nn < N) ? x[(size_t)nn * F + (i % F)] : 0.0f;
    }
    __syncthreads();
    int n = n0 + w;
    if (n >= N) return;
    int t = types[n];
    const float* W = W_in + (size_t)t * F * HID;
    float acc = b_in[t * HID + h];
    const float* xr = xs + w * F;
    #pragma unroll 4
    for (int f = 0; f < F; ++f)
        acc = fmaf(xr[f], W[(size_t)f * HID + h], acc);
    hid[(size_t)n * HID + h] = acc;
}

// ---------------- layer 1: two gathers + W0/W1 matvec + max ----------------
__global__ void layer1(const float* __restrict__ hid,
                       const int* __restrict__ off0, const int* __restrict__ csr0,
                       const float* __restrict__ dinv0,
                       const int* __restrict__ off1, const int* __restrict__ csr1,
                       const float* __restrict__ dinv1,
                       const float* __restrict__ W_conv, const float* __restrict__ b_conv,
                       float* __restrict__ t0, float* __restrict__ s1out, int N) {
    __shared__ float l0[4][HID], l1[4][HID];
    int w = threadIdx.x >> 6, h = threadIdx.x & 63;
    int n = blockIdx.x * 4 + w;
    if (n >= N) return;
    float d0 = dinv0[n], d1 = dinv1[n];
    float self = hid[(size_t)n * HID + h];
    float acc0 = self * d0 * d0;
    float acc1 = self * d1 * d1;
    {
        int e = off0[n], e_ = off0[n + 1];
        for (; e + 3 < e_; e += 4) {
            int a = csr0[e], b = csr0[e + 1], c = csr0[e + 2], d = csr0[e + 3];
            float wa = dinv0[a] * d0, wb = dinv0[b] * d0, wc = dinv0[c] * d0, wd = dinv0[d] * d0;
            acc0 += hid[(size_t)a * HID + h] * wa;
            acc0 += hid[(size_t)b * HID + h] * wb;
            acc0 += hid[(size_t)c * HID + h] * wc;
            acc0 += hid[(size_t)d * HID + h] * wd;
        }
        for (; e < e_; ++e) {
            int a = csr0[e];
            acc0 += hid[(size_t)a * HID + h] * (dinv0[a] * d0);
        }
    }
    {
        int e = off1[n], e_ = off1[n + 1];
        for (; e + 3 < e_; e += 4) {
            int a = csr1[e], b = csr1[e + 1], c = csr1[e + 2], d = csr1[e + 3];
            float wa = dinv1[a] * d1, wb = dinv1[b] * d1, wc = dinv1[c] * d1, wd = dinv1[d] * d1;
            acc1 += hid[(size_t)a * HID + h] * wa;
            acc1 += hid[(size_t)b * HID + h] * wb;
            acc1 += hid[(size_t)c * HID + h] * wc;
            acc1 += hid[(size_t)d * HID + h] * wd;
        }
        for (; e < e_; ++e) {
            int a = csr1[e];
            acc1 += hid[(size_t)a * HID + h] * (dinv1[a] * d1);
        }
    }
    t0[(size_t)n * HID + h] = acc0;     // agg0 reused by layer 2
    l0[w][h] = acc0;
    l1[w][h] = acc1;
    const float* W0 = W_conv;
    const float* W1 = W_conv + HID * HID;
    float m0 = b_conv[h];
    float m1 = b_conv[HID + h];
    #pragma unroll 8
    for (int k = 0; k < HID; ++k) {
        m0 = fmaf(l0[w][k], W0[k * HID + h], m0);
        m1 = fmaf(l1[w][k], W1[k * HID + h], m1);
    }
    s1out[(size_t)n * HID + h] = fmaxf(m0, m1);
}

// ------- layer 2: gather(s1, csr0) + W2/W3c matvec + max + LN + gelu + W3 -------
__global__ void layer2(const float* __restrict__ t0, const float* __restrict__ s1in,
                       const int* __restrict__ off0, const int* __restrict__ csr0,
                       const float* __restrict__ dinv0,
                       const float* __restrict__ W_conv, const float* __restrict__ b_conv,
                       const float* __restrict__ W3, const float* __restrict__ b3,
                       float* __restrict__ out, int N) {
    __shared__ float l2[4][HID], l3[4][HID], gs[4][HID];
    int w = threadIdx.x >> 6, h = threadIdx.x & 63;
    int n = blockIdx.x * 4 + w;
    if (n >= N) return;
    float d0 = dinv0[n];
    float selfv = s1in[(size_t)n * HID + h];
    float acc = selfv * d0 * d0;
    {
        int e = off0[n], e_ = off0[n + 1];
        for (; e + 3 < e_; e += 4) {
            int a = csr0[e], b = csr0[e + 1], c = csr0[e + 2], d = csr0[e + 3];
            float wa = dinv0[a] * d0, wb = dinv0[b] * d0, wc = dinv0[c] * d0, wd = dinv0[d] * d0;
            acc += s1in[(size_t)a * HID + h] * wa;
            acc += s1in[(size_t)b * HID + h] * wb;
            acc += s1in[(size_t)c * HID + h] * wc;
            acc += s1in[(size_t)d * HID + h] * wd;
        }
        for (; e < e_; ++e) {
            int a = csr0[e];
            acc += s1in[(size_t)a * HID + h] * (dinv0[a] * d0);
        }
    }
    l3[w][h] = acc;
    l2[w][h] = t0[(size_t)n * HID + h];
    const float* W2  = W_conv + 2 * HID * HID;
    const float* W3c = W_conv + 3 * HID * HID;
    float m2 = b_conv[2 * HID + h];
    float m3 = b_conv[3 * HID + h];
    #pragma unroll 8
    for (int k = 0; k < HID; ++k) {
        m2 = fmaf(l2[w][k], W2[k * HID + h], m2);
        m3 = fmaf(l3[w][k], W3c[k * HID + h], m3);
    }
    float s2 = fmaxf(m2, m3);
    float sum = s2;
    #pragma unroll
    for (int off = 32; off; off >>= 1) sum += __shfl_xor(sum, off, 64);
    float mu = sum * (1.0f / 64.0f);
    float dv = s2 - mu;
    float v = dv * dv;
    #pragma unroll
    for (int off = 32; off; off >>= 1) v += __shfl_xor(v, off, 64);
    float xn = dv * rsqrtf(v * (1.0f / 64.0f) + 1e-5f);
    float g = 0.5f * xn * (1.0f + erff(xn * 0.70710678118654752f));
    gs[w][h] = g;
    if (h < 8) {
        float a = b3[h];
        #pragma unroll 8
        for (int k = 0; k < HID; ++k)
            a = fmaf(gs[w][k], W3[k * 8 + h], a);
        out[(size_t)n * 8 + h] = a;
    }
}

extern "C" void kernel_launch(void* const* d_in, const int* in_sizes, int n_in,
                              void* d_out, int out_size, void* d_ws, size_t ws_size,
                              hipStream_t stream) {
    const float* x          = (const float*)d_in[0];
    const int*   node_types = (const int*)d_in[1];
    const int*   e0         = (const int*)d_in[2];   // (2,E): [0..E)=src, [E..2E)=dst
    const int*   e1         = (const int*)d_in[3];
    const float* W_in       = (const float*)d_in[4];
    const float* b_in       = (const float*)d_in[5];
    const float* W_conv     = (const float*)d_in[6];
    const float* b_conv     = (const float*)d_in[7];
    const float* W3         = (const float*)d_in[12];
    const float* b3         = (const float*)d_in[13];
    float* out = (float*)d_out;

    int N = in_sizes[1];
    int F = in_sizes[0] / N;    // 128
    int E = in_sizes[2] / 2;    // 1.6M
    int BW = (N + RB - 1) / RB; // 782 (fits LDS arrays of 800)

    // workspace layout (4-byte units); arena aliases t0 (both 25.6 MB)
    int*   bcnt  = (int*)d_ws;                 // 2*RB
    int*   bbase = bcnt + 2 * RB;              // 2*(RB+1)
    int*   bcur  = bbase + 2 * (RB + 1);       // 2*RB, then pad
    int*   off0  = bcur + 2 * RB + 6;          // N+1
    int*   off1  = off0 + (N + 1);             // N+1
    float* dinv0 = (float*)(off1 + (N + 1));   // N
    float* dinv1 = dinv0 + N;                  // N
    int*   csr0  = (int*)(dinv1 + N);          // E
    int*   csr1  = csr0 + E;                   // E
    float* hid   = (float*)(csr1 + E);         // 64N
    float* t0    = hid + (size_t)HID * N;      // 64N == 2E uint2 (arena alias)
    float* s1    = t0 + (size_t)HID * N;       // 64N
    uint2* arena = (uint2*)t0;                 // 2 lists × E pairs

    hipMemsetAsync(bcnt, 0, 2 * RB * sizeof(int), stream);
    histA<<<1024, 256, 0, stream>>>(e0 + E, e1 + E, E, BW, bcnt);
    scanA<<<1, 256, 0, stream>>>(bcnt, bbase, bcur, E, off0, off1, N);
    partB<<<256, 256, 0, stream>>>(e0, e1, E, BW, bcur, arena);
    buildC<<<2 * RB, 1024, 0, stream>>>(arena, bbase, E, N, BW,
                                        csr0, csr1, off0, off1, dinv0, dinv1);
    input_proj<<<(N + 3) / 4, 256, 0, stream>>>(x, node_types, W_in, b_in, hid, N, F);
    layer1<<<(N + 3) / 4, 256, 0, stream>>>(hid, off0, csr0, dinv0, off1, csr1, dinv1,
                                            W_conv, b_conv, t0, s1, N);
    layer2<<<(N + 3) / 4, 256, 0, stream>>>(t0, s1, off0, csr0, dinv0,
                                            W_conv, b_conv, W3, b3, out, N);
}

// Round 8
// 571.642 us; speedup vs baseline: 2.9328x; 1.1112x over previous
//
#include <hip/hip_runtime.h>
#include <hip/hip_bf16.h>
#include <math.h>

// HGNN forward, MI355X — round 8: identical to rounds 6/7 (infra flake re-runs).
// bf16 pre-scaled gather features (g0=hid*dinv0, g1=hid*dinv1, s1g=s1*dinv0
// -> 128B rows, no per-edge norm), packed u32 edge arena, magic-div buckets.
// Pipeline: memset -> histA -> scanA -> partB -> buildC
//           -> input_proj (writes g0,g1 bf16) -> layer1 -> layer2
// attn == softmax over size-1 axis == 1.0 exactly, so W1/b1/W2/b2 are unused.

#define HID   64
#define RB    128     // buckets per edge list
#define CHUNK 4096    // edges per block-chunk in partB (16/thread)

__device__ __forceinline__ float bf2f(ushort v) {
    unsigned u = ((unsigned)v) << 16;
    return __int_as_float((int)u);
}
// round-to-nearest-even f32 -> bf16 (matches HW cvt)
__device__ __forceinline__ ushort f2bf(float f) {
    unsigned u = __float_as_uint(f);
    unsigned r = u + 0x7FFFu + ((u >> 16) & 1u);
    return (ushort)(r >> 16);
}

// ---------------- bucket histogram ----------------
__global__ void histA(const int* __restrict__ dst0, const int* __restrict__ dst1,
                      int E, unsigned M, int* __restrict__ bcnt) {
    __shared__ int h[2 * RB];
    for (int i = threadIdx.x; i < 2 * RB; i += blockDim.x) h[i] = 0;
    __syncthreads();
    int stride = gridDim.x * blockDim.x;
    for (int i = blockIdx.x * blockDim.x + threadIdx.x; i < E; i += stride) {
        atomicAdd(&h[__umulhi((unsigned)dst0[i], M)], 1);
        atomicAdd(&h[RB + __umulhi((unsigned)dst1[i], M)], 1);
    }
    __syncthreads();
    for (int i = threadIdx.x; i < 2 * RB; i += blockDim.x)
        if (h[i]) atomicAdd(&bcnt[i], h[i]);
}

// ---------------- bucket scan (256 elements, 1 block of 256) ----------------
__global__ void scanA(const int* __restrict__ bcnt, int* __restrict__ bbase,
                      int* __restrict__ bcur, int E,
                      int* __restrict__ off0, int* __restrict__ off1, int N) {
    __shared__ int t[2 * RB];
    int tid = threadIdx.x;
    int orig = bcnt[tid];
    t[tid] = orig;
    __syncthreads();
    int list = tid >> 7, r = tid & (RB - 1);
    for (int o = 1; o < RB; o <<= 1) {
        int u = (r >= o) ? t[tid - o] : 0;
        __syncthreads();
        t[tid] += u;
        __syncthreads();
    }
    int incl = t[tid];
    int excl = incl - orig;
    bbase[list * (RB + 1) + r] = excl;
    bcur[tid] = excl;
    if (r == RB - 1) bbase[list * (RB + 1) + RB] = incl;   // == E
    if (tid == 0) { off0[N] = E; off1[N] = E; }
}

// ------- partition: chunked counting sort -> bucket-ordered packed arena -------
__global__ void __launch_bounds__(256) partB(const int* __restrict__ e0,
                                             const int* __restrict__ e1,
                                             int E, int BW, unsigned M,
                                             int* __restrict__ bcur_all,
                                             unsigned* __restrict__ arena_all) {
    __shared__ int hist[RB], scn[RB], lbase[RB], cur[RB], gbase[RB];
    __shared__ uint2 buf[CHUNK];                  // 32 KB
    int half = gridDim.x >> 1;
    int list = (blockIdx.x >= half) ? 1 : 0;
    const int* src = list ? e1 : e0;
    const int* dst = src + E;
    int* bcur = bcur_all + list * RB;
    unsigned* arena = arena_all + (size_t)list * E;
    int blk = blockIdx.x - list * half;
    int tid = threadIdx.x;

    for (int c0 = blk * CHUNK; c0 < E; c0 += half * CHUNK) {
        int cn = min(CHUNK, E - c0);
        for (int i = tid; i < RB; i += 256) hist[i] = 0;
        __syncthreads();
        unsigned ls[16], ld[16];
        #pragma unroll
        for (int k = 0; k < 16; ++k) {
            int j = k * 256 + tid;
            ld[k] = 0xFFFFFFFFu; ls[k] = 0;
            if (j < cn) {
                ls[k] = (unsigned)src[c0 + j];
                ld[k] = (unsigned)dst[c0 + j];
                atomicAdd(&hist[__umulhi(ld[k], M)], 1);
            }
        }
        __syncthreads();
        if (tid < RB) scn[tid] = hist[tid];
        __syncthreads();
        for (int o = 1; o < RB; o <<= 1) {
            int u = (tid < RB && tid >= o) ? scn[tid - o] : 0;
            __syncthreads();
            if (tid < RB) scn[tid] += u;
            __syncthreads();
        }
        if (tid < RB) {
            int ex = scn[tid] - hist[tid];
            lbase[tid] = ex;
            cur[tid]   = ex;
            gbase[tid] = hist[tid] ? atomicAdd(&bcur[tid], hist[tid]) : 0;
        }
        __syncthreads();
        #pragma unroll
        for (int k = 0; k < 16; ++k) {
            if (ld[k] != 0xFFFFFFFFu) {
                int b = __umulhi(ld[k], M);
                int slot = atomicAdd(&cur[b], 1);
                buf[slot] = make_uint2(ls[k], ld[k]);
            }
        }
        __syncthreads();
        for (int i = tid; i < cn; i += 256) {
            uint2 p = buf[i];
            int b = __umulhi(p.y, M);
            arena[gbase[b] + (i - lbase[b])] = (p.x << 10) | (p.y - (unsigned)(b * BW));
        }
        __syncthreads();
    }
}

// ------- per-bucket CSR build: degree, scan, off, dinv, fill — all in LDS -------
__global__ void __launch_bounds__(1024) buildC(const unsigned* __restrict__ arena_all,
                                               const int* __restrict__ bbase,
                                               int E, int N, int BW,
                                               int* __restrict__ csr0, int* __restrict__ csr1,
                                               int* __restrict__ off0, int* __restrict__ off1,
                                               float* __restrict__ dinv0, float* __restrict__ dinv1) {
    __shared__ int degl[800], scn[800], cur[800];
    int list = blockIdx.x >> 7, rb = blockIdx.x & (RB - 1);
    const unsigned* arena = arena_all + (size_t)list * E;
    int* csr = list ? csr1 : csr0;
    int* off = list ? off1 : off0;
    float* dinv = list ? dinv1 : dinv0;
    int base = bbase[list * (RB + 1) + rb];
    int end  = bbase[list * (RB + 1) + rb + 1];
    int nbase = rb * BW;
    int nn = min(BW, N - nbase);
    if (nn <= 0) return;
    int tid = threadIdx.x;
    for (int i = tid; i < nn; i += 1024) degl[i] = 0;
    __syncthreads();
    for (int j = base + tid; j < end; j += 1024)
        atomicAdd(&degl[arena[j] & 1023u], 1);
    __syncthreads();
    int v0 = (tid < nn) ? degl[tid] : 0;
    if (tid < nn) scn[tid] = v0;
    __syncthreads();
    for (int o = 1; o < nn; o <<= 1) {
        int u = (tid < nn && tid >= o) ? scn[tid - o] : 0;
        __syncthreads();
        if (tid < nn) scn[tid] += u;
        __syncthreads();
    }
    if (tid < nn) {
        int ex = scn[tid] - v0;                 // exclusive
        cur[tid] = ex;
        off[nbase + tid] = base + ex;
        dinv[nbase + tid] = rsqrtf((float)(v0 + 1));
    }
    __syncthreads();
    for (int j = base + tid; j < end; j += 1024) {
        unsigned p = arena[j];
        int loc = atomicAdd(&cur[p & 1023u], 1);
        csr[base + loc] = (int)(p >> 10);
    }
}

// ------ input projection: g0 = bf16((x@W+b)*dinv0), g1 = bf16(...*dinv1) ------
__global__ void input_proj(const float* __restrict__ x, const int* __restrict__ types,
                           const float* __restrict__ W_in, const float* __restrict__ b_in,
                           const float* __restrict__ dinv0, const float* __restrict__ dinv1,
                           ushort* __restrict__ g0, ushort* __restrict__ g1,
                           int N, int F) {
    __shared__ float xs[4 * 128];   // F == 128
    int tid = threadIdx.x;
    int w = tid >> 6, h = tid & 63;
    int n0 = blockIdx.x * 4;
    for (int i = tid; i < 4 * F; i += 256) {
        int nn = n0 + i / F;
        xs[i] = (nn < N) ? x[(size_t)nn * F + (i % F)] : 0.0f;
    }
    __syncthreads();
    int n = n0 + w;
    if (n >= N) return;
    int t = types[n];
    const float* W = W_in + (size_t)t * F * HID;
    float acc = b_in[t * HID + h];
    const float* xr = xs + w * F;
    #pragma unroll 4
    for (int f = 0; f < F; ++f)
        acc = fmaf(xr[f], W[(size_t)f * HID + h], acc);
    size_t idx = (size_t)n * HID + h;
    g0[idx] = f2bf(acc * dinv0[n]);
    g1[idx] = f2bf(acc * dinv1[n]);
}

// ---------------- layer 1: two bf16 gathers + W0/W1 matvec + max ----------------
__global__ void layer1(const ushort* __restrict__ g0, const ushort* __restrict__ g1,
                       const int* __restrict__ off0, const int* __restrict__ csr0,
                       const float* __restrict__ dinv0,
                       const int* __restrict__ off1, const int* __restrict__ csr1,
                       const float* __restrict__ dinv1,
                       const float* __restrict__ W_conv, const float* __restrict__ b_conv,
                       float* __restrict__ t0, ushort* __restrict__ s1g, int N) {
    __shared__ float l0[4][HID], l1[4][HID];
    int w = threadIdx.x >> 6, h = threadIdx.x & 63;
    int n = blockIdx.x * 4 + w;
    if (n >= N) return;
    float d0 = dinv0[n], d1 = dinv1[n];
    float acc0 = bf2f(g0[(size_t)n * HID + h]);   // self term
    float acc1 = bf2f(g1[(size_t)n * HID + h]);
    {
        int e = off0[n], e_ = off0[n + 1];
        for (; e + 3 < e_; e += 4) {
            int a = csr0[e], b = csr0[e + 1], c = csr0[e + 2], d = csr0[e + 3];
            acc0 += bf2f(g0[(size_t)a * HID + h]);
            acc0 += bf2f(g0[(size_t)b * HID + h]);
            acc0 += bf2f(g0[(size_t)c * HID + h]);
            acc0 += bf2f(g0[(size_t)d * HID + h]);
        }
        for (; e < e_; ++e)
            acc0 += bf2f(g0[(size_t)csr0[e] * HID + h]);
    }
    {
        int e = off1[n], e_ = off1[n + 1];
        for (; e + 3 < e_; e += 4) {
            int a = csr1[e], b = csr1[e + 1], c = csr1[e + 2], d = csr1[e + 3];
            acc1 += bf2f(g1[(size_t)a * HID + h]);
            acc1 += bf2f(g1[(size_t)b * HID + h]);
            acc1 += bf2f(g1[(size_t)c * HID + h]);
            acc1 += bf2f(g1[(size_t)d * HID + h]);
        }
        for (; e < e_; ++e)
            acc1 += bf2f(g1[(size_t)csr1[e] * HID + h]);
    }
    acc0 *= d0;
    acc1 *= d1;
    t0[(size_t)n * HID + h] = acc0;     // agg0 (fp32) reused by layer 2
    l0[w][h] = acc0;
    l1[w][h] = acc1;
    const float* W0 = W_conv;
    const float* W1 = W_conv + HID * HID;
    float m0 = b_conv[h];
    float m1 = b_conv[HID + h];
    #pragma unroll 8
    for (int k = 0; k < HID; ++k) {
        m0 = fmaf(l0[w][k], W0[k * HID + h], m0);
        m1 = fmaf(l1[w][k], W1[k * HID + h], m1);
    }
    s1g[(size_t)n * HID + h] = f2bf(fmaxf(m0, m1) * d0);
}

// ------- layer 2: bf16 gather(s1g, csr0) + W2/W3c matvec + max + LN + gelu + W3 -------
__global__ void layer2(const float* __restrict__ t0, const ushort* __restrict__ s1g,
                       const int* __restrict__ off0, const int* __restrict__ csr0,
                       const float* __restrict__ dinv0,
                       const float* __restrict__ W_conv, const float* __restrict__ b_conv,
                       const float* __restrict__ W3, const float* __restrict__ b3,
                       float* __restrict__ out, int N) {
    __shared__ float l2[4][HID], l3[4][HID], gs[4][HID];
    int w = threadIdx.x >> 6, h = threadIdx.x & 63;
    int n = blockIdx.x * 4 + w;
    if (n >= N) return;
    float d0 = dinv0[n];
    float acc = bf2f(s1g[(size_t)n * HID + h]);   // self term
    {
        int e = off0[n], e_ = off0[n + 1];
        for (; e + 3 < e_; e += 4) {
            int a = csr0[e], b = csr0[e + 1], c = csr0[e + 2], d = csr0[e + 3];
            acc += bf2f(s1g[(size_t)a * HID + h]);
            acc += bf2f(s1g[(size_t)b * HID + h]);
            acc += bf2f(s1g[(size_t)c * HID + h]);
            acc += bf2f(s1g[(size_t)d * HID + h]);
        }
        for (; e < e_; ++e)
            acc += bf2f(s1g[(size_t)csr0[e] * HID + h]);
    }
    acc *= d0;
    l3[w][h] = acc;
    l2[w][h] = t0[(size_t)n * HID + h];
    const float* W2  = W_conv + 2 * HID * HID;
    const float* W3c = W_conv + 3 * HID * HID;
    float m2 = b_conv[2 * HID + h];
    float m3 = b_conv[3 * HID + h];
    #pragma unroll 8
    for (int k = 0; k < HID; ++k) {
        m2 = fmaf(l2[w][k], W2[k * HID + h], m2);
        m3 = fmaf(l3[w][k], W3c[k * HID + h], m3);
    }
    float s2 = fmaxf(m2, m3);
    float sum = s2;
    #pragma unroll
    for (int off = 32; off; off >>= 1) sum += __shfl_xor(sum, off, 64);
    float mu = sum * (1.0f / 64.0f);
    float dv = s2 - mu;
    float v = dv * dv;
    #pragma unroll
    for (int off = 32; off; off >>= 1) v += __shfl_xor(v, off, 64);
    float xn = dv * rsqrtf(v * (1.0f / 64.0f) + 1e-5f);
    float g = 0.5f * xn * (1.0f + erff(xn * 0.70710678118654752f));
    gs[w][h] = g;
    if (h < 8) {
        float a = b3[h];
        #pragma unroll 8
        for (int k = 0; k < HID; ++k)
            a = fmaf(gs[w][k], W3[k * 8 + h], a);
        out[(size_t)n * 8 + h] = a;
    }
}

extern "C" void kernel_launch(void* const* d_in, const int* in_sizes, int n_in,
                              void* d_out, int out_size, void* d_ws, size_t ws_size,
                              hipStream_t stream) {
    const float* x          = (const float*)d_in[0];
    const int*   node_types = (const int*)d_in[1];
    const int*   e0         = (const int*)d_in[2];   // (2,E): [0..E)=src, [E..2E)=dst
    const int*   e1         = (const int*)d_in[3];
    const float* W_in       = (const float*)d_in[4];
    const float* b_in       = (const float*)d_in[5];
    const float* W_conv     = (const float*)d_in[6];
    const float* b_conv     = (const float*)d_in[7];
    const float* W3         = (const float*)d_in[12];
    const float* b3         = (const float*)d_in[13];
    float* out = (float*)d_out;

    int N = in_sizes[1];
    int F = in_sizes[0] / N;    // 128
    int E = in_sizes[2] / 2;    // 1.6M
    int BW = (N + RB - 1) / RB; // 782 (< 1024 for packing)
    unsigned M = (unsigned)(0x100000000ULL / (unsigned long long)BW) + 1u;  // magic div

    // workspace layout (4-byte units); arena aliases t0
    int*   bcnt  = (int*)d_ws;                 // 2*RB
    int*   bbase = bcnt + 2 * RB;              // 2*(RB+1)
    int*   bcur  = bbase + 2 * (RB + 1);       // 2*RB, pad
    int*   off0  = bcur + 2 * RB + 6;          // N+1
    int*   off1  = off0 + (N + 1);             // N+1
    float* dinv0 = (float*)(off1 + (N + 1));   // N
    float* dinv1 = dinv0 + N;                  // N
    int*   csr0  = (int*)(dinv1 + N);          // E
    int*   csr1  = csr0 + E;                   // E
    ushort* g0   = (ushort*)(csr1 + E);        // 64N bf16
    ushort* g1   = g0 + (size_t)HID * N;       // 64N bf16
    float* t0    = (float*)(g1 + (size_t)HID * N);  // 64N fp32 (aliases arena)
    ushort* s1g  = (ushort*)(t0 + (size_t)HID * N); // 64N bf16
    unsigned* arena = (unsigned*)t0;           // 2 lists × E u32 (dead before layer1)

    (void)hipMemsetAsync(bcnt, 0, 2 * RB * sizeof(int), stream);
    histA<<<1024, 256, 0, stream>>>(e0 + E, e1 + E, E, M, bcnt);
    scanA<<<1, 256, 0, stream>>>(bcnt, bbase, bcur, E, off0, off1, N);
    partB<<<256, 256, 0, stream>>>(e0, e1, E, BW, M, bcur, arena);
    buildC<<<2 * RB, 1024, 0, stream>>>(arena, bbase, E, N, BW,
                                        csr0, csr1, off0, off1, dinv0, dinv1);
    input_proj<<<(N + 3) / 4, 256, 0, stream>>>(x, node_types, W_in, b_in,
                                                dinv0, dinv1, g0, g1, N, F);
    layer1<<<(N + 3) / 4, 256, 0, stream>>>(g0, g1, off0, csr0, dinv0, off1, csr1, dinv1,
                                            W_conv, b_conv, t0, s1g, N);
    layer2<<<(N + 3) / 4, 256, 0, stream>>>(t0, s1g, off0, csr0, dinv0,
                                            W_conv, b_conv, W3, b3, out, N);
}

// Round 9
// 543.287 us; speedup vs baseline: 3.0859x; 1.0522x over previous
//
#include <hip/hip_runtime.h>
#include <hip/hip_bf16.h>
#include <math.h>

// HGNN forward, MI355X — round 9: 4-edges-per-instruction gather (uint2/lane,
// 16 lanes per 128B row) with 8-edge pipelined loop -> 4x memory-level
// parallelism in layer1/layer2. Construction pipeline unchanged from r8.
// attn == softmax over size-1 axis == 1.0 exactly, so W1/b1/W2/b2 are unused.

#define HID   64
#define RB    128     // buckets per edge list
#define CHUNK 4096    // edges per block-chunk in partB (16/thread)

__device__ __forceinline__ float bf2f(ushort v) {
    unsigned u = ((unsigned)v) << 16;
    return __int_as_float((int)u);
}
// round-to-nearest-even f32 -> bf16 (matches HW cvt)
__device__ __forceinline__ ushort f2bf(float f) {
    unsigned u = __float_as_uint(f);
    unsigned r = u + 0x7FFFu + ((u >> 16) & 1u);
    return (ushort)(r >> 16);
}
// accumulate 4 bf16 (one uint2) into float[4]
__device__ __forceinline__ void addbf(float a[4], uint2 v) {
    a[0] += __int_as_float((int)(v.x << 16));
    a[1] += __int_as_float((int)(v.x & 0xFFFF0000u));
    a[2] += __int_as_float((int)(v.y << 16));
    a[3] += __int_as_float((int)(v.y & 0xFFFF0000u));
}

// ---------------- bucket histogram ----------------
__global__ void histA(const int* __restrict__ dst0, const int* __restrict__ dst1,
                      int E, unsigned M, int* __restrict__ bcnt) {
    __shared__ int h[2 * RB];
    for (int i = threadIdx.x; i < 2 * RB; i += blockDim.x) h[i] = 0;
    __syncthreads();
    int stride = gridDim.x * blockDim.x;
    for (int i = blockIdx.x * blockDim.x + threadIdx.x; i < E; i += stride) {
        atomicAdd(&h[__umulhi((unsigned)dst0[i], M)], 1);
        atomicAdd(&h[RB + __umulhi((unsigned)dst1[i], M)], 1);
    }
    __syncthreads();
    for (int i = threadIdx.x; i < 2 * RB; i += blockDim.x)
        if (h[i]) atomicAdd(&bcnt[i], h[i]);
}

// ---------------- bucket scan (256 elements, 1 block of 256) ----------------
__global__ void scanA(const int* __restrict__ bcnt, int* __restrict__ bbase,
                      int* __restrict__ bcur, int E,
                      int* __restrict__ off0, int* __restrict__ off1, int N) {
    __shared__ int t[2 * RB];
    int tid = threadIdx.x;
    int orig = bcnt[tid];
    t[tid] = orig;
    __syncthreads();
    int list = tid >> 7, r = tid & (RB - 1);
    for (int o = 1; o < RB; o <<= 1) {
        int u = (r >= o) ? t[tid - o] : 0;
        __syncthreads();
        t[tid] += u;
        __syncthreads();
    }
    int incl = t[tid];
    int excl = incl - orig;
    bbase[list * (RB + 1) + r] = excl;
    bcur[tid] = excl;
    if (r == RB - 1) bbase[list * (RB + 1) + RB] = incl;   // == E
    if (tid == 0) { off0[N] = E; off1[N] = E; }
}

// ------- partition: chunked counting sort -> bucket-ordered packed arena -------
__global__ void __launch_bounds__(256) partB(const int* __restrict__ e0,
                                             const int* __restrict__ e1,
                                             int E, int BW, unsigned M,
                                             int* __restrict__ bcur_all,
                                             unsigned* __restrict__ arena_all) {
    __shared__ int hist[RB], scn[RB], lbase[RB], cur[RB], gbase[RB];
    __shared__ uint2 buf[CHUNK];                  // 32 KB
    int half = gridDim.x >> 1;
    int list = (blockIdx.x >= half) ? 1 : 0;
    const int* src = list ? e1 : e0;
    const int* dst = src + E;
    int* bcur = bcur_all + list * RB;
    unsigned* arena = arena_all + (size_t)list * E;
    int blk = blockIdx.x - list * half;
    int tid = threadIdx.x;

    for (int c0 = blk * CHUNK; c0 < E; c0 += half * CHUNK) {
        int cn = min(CHUNK, E - c0);
        for (int i = tid; i < RB; i += 256) hist[i] = 0;
        __syncthreads();
        unsigned ls[16], ld[16];
        #pragma unroll
        for (int k = 0; k < 16; ++k) {
            int j = k * 256 + tid;
            ld[k] = 0xFFFFFFFFu; ls[k] = 0;
            if (j < cn) {
                ls[k] = (unsigned)src[c0 + j];
                ld[k] = (unsigned)dst[c0 + j];
                atomicAdd(&hist[__umulhi(ld[k], M)], 1);
            }
        }
        __syncthreads();
        if (tid < RB) scn[tid] = hist[tid];
        __syncthreads();
        for (int o = 1; o < RB; o <<= 1) {
            int u = (tid < RB && tid >= o) ? scn[tid - o] : 0;
            __syncthreads();
            if (tid < RB) scn[tid] += u;
            __syncthreads();
        }
        if (tid < RB) {
            int ex = scn[tid] - hist[tid];
            lbase[tid] = ex;
            cur[tid]   = ex;
            gbase[tid] = hist[tid] ? atomicAdd(&bcur[tid], hist[tid]) : 0;
        }
        __syncthreads();
        #pragma unroll
        for (int k = 0; k < 16; ++k) {
            if (ld[k] != 0xFFFFFFFFu) {
                int b = __umulhi(ld[k], M);
                int slot = atomicAdd(&cur[b], 1);
                buf[slot] = make_uint2(ls[k], ld[k]);
            }
        }
        __syncthreads();
        for (int i = tid; i < cn; i += 256) {
            uint2 p = buf[i];
            int b = __umulhi(p.y, M);
            arena[gbase[b] + (i - lbase[b])] = (p.x << 10) | (p.y - (unsigned)(b * BW));
        }
        __syncthreads();
    }
}

// ------- per-bucket CSR build: degree, scan, off, dinv, fill — all in LDS -------
__global__ void __launch_bounds__(1024) buildC(const unsigned* __restrict__ arena_all,
                                               const int* __restrict__ bbase,
                                               int E, int N, int BW,
                                               int* __restrict__ csr0, int* __restrict__ csr1,
                                               int* __restrict__ off0, int* __restrict__ off1,
                                               float* __restrict__ dinv0, float* __restrict__ dinv1) {
    __shared__ int degl[800], scn[800], cur[800];
    int list = blockIdx.x >> 7, rb = blockIdx.x & (RB - 1);
    const unsigned* arena = arena_all + (size_t)list * E;
    int* csr = list ? csr1 : csr0;
    int* off = list ? off1 : off0;
    float* dinv = list ? dinv1 : dinv0;
    int base = bbase[list * (RB + 1) + rb];
    int end  = bbase[list * (RB + 1) + rb + 1];
    int nbase = rb * BW;
    int nn = min(BW, N - nbase);
    if (nn <= 0) return;
    int tid = threadIdx.x;
    for (int i = tid; i < nn; i += 1024) degl[i] = 0;
    __syncthreads();
    for (int j = base + tid; j < end; j += 1024)
        atomicAdd(&degl[arena[j] & 1023u], 1);
    __syncthreads();
    int v0 = (tid < nn) ? degl[tid] : 0;
    if (tid < nn) scn[tid] = v0;
    __syncthreads();
    for (int o = 1; o < nn; o <<= 1) {
        int u = (tid < nn && tid >= o) ? scn[tid - o] : 0;
        __syncthreads();
        if (tid < nn) scn[tid] += u;
        __syncthreads();
    }
    if (tid < nn) {
        int ex = scn[tid] - v0;                 // exclusive
        cur[tid] = ex;
        off[nbase + tid] = base + ex;
        dinv[nbase + tid] = rsqrtf((float)(v0 + 1));
    }
    __syncthreads();
    for (int j = base + tid; j < end; j += 1024) {
        unsigned p = arena[j];
        int loc = atomicAdd(&cur[p & 1023u], 1);
        csr[base + loc] = (int)(p >> 10);
    }
}

// ------ input projection: g0 = bf16((x@W+b)*dinv0), g1 = bf16(...*dinv1) ------
__global__ void input_proj(const float* __restrict__ x, const int* __restrict__ types,
                           const float* __restrict__ W_in, const float* __restrict__ b_in,
                           const float* __restrict__ dinv0, const float* __restrict__ dinv1,
                           ushort* __restrict__ g0, ushort* __restrict__ g1,
                           int N, int F) {
    __shared__ float xs[4 * 128];   // F == 128
    int tid = threadIdx.x;
    int w = tid >> 6, h = tid & 63;
    int n0 = blockIdx.x * 4;
    for (int i = tid; i < 4 * F; i += 256) {
        int nn = n0 + i / F;
        xs[i] = (nn < N) ? x[(size_t)nn * F + (i % F)] : 0.0f;
    }
    __syncthreads();
    int n = n0 + w;
    if (n >= N) return;
    int t = types[n];
    const float* W = W_in + (size_t)t * F * HID;
    float acc = b_in[t * HID + h];
    const float* xr = xs + w * F;
    #pragma unroll 4
    for (int f = 0; f < F; ++f)
        acc = fmaf(xr[f], W[(size_t)f * HID + h], acc);
    size_t idx = (size_t)n * HID + h;
    g0[idx] = f2bf(acc * dinv0[n]);
    g1[idx] = f2bf(acc * dinv1[n]);
}

// ------- layer 1: two 4-edge-wide bf16 gathers + W0/W1 matvec + max -------
__global__ void layer1(const ushort* __restrict__ g0, const ushort* __restrict__ g1,
                       const int* __restrict__ off0, const int* __restrict__ csr0,
                       const float* __restrict__ dinv0,
                       const int* __restrict__ off1, const int* __restrict__ csr1,
                       const float* __restrict__ dinv1,
                       const float* __restrict__ W_conv, const float* __restrict__ b_conv,
                       float* __restrict__ t0, ushort* __restrict__ s1g, int N) {
    __shared__ float l0[4][HID], l1[4][HID];
    int w = threadIdx.x >> 6, lane = threadIdx.x & 63;
    int n = blockIdx.x * 4 + w;
    if (n >= N) return;
    int q = lane >> 4, fl = lane & 15;       // edge slot, feature quad
    const uint2* G0 = (const uint2*)g0;      // row = 16 uint2 (128 B)
    const uint2* G1 = (const uint2*)g1;
    float a0[4] = {0, 0, 0, 0}, a1[4] = {0, 0, 0, 0};
    if (q == 0) {                            // self term counted once
        addbf(a0, G0[(size_t)n * 16 + fl]);
        addbf(a1, G1[(size_t)n * 16 + fl]);
    }
    {   // list 0: 8 edges per iteration, 4 per load instruction
        int e = off0[n], e_ = off0[n + 1];
        for (; e + 8 <= e_; e += 8) {
            int ia = csr0[e + q], ib = csr0[e + 4 + q];
            uint2 va = G0[(size_t)ia * 16 + fl];
            uint2 vb = G0[(size_t)ib * 16 + fl];
            addbf(a0, va); addbf(a0, vb);
        }
        if (e + 4 <= e_) {
            int ia = csr0[e + q];
            addbf(a0, G0[(size_t)ia * 16 + fl]);
            e += 4;
        }
        int rem = e_ - e;
        if (rem > 0) {
            int ia = csr0[e + (q < rem ? q : rem - 1)];
            uint2 va = G0[(size_t)ia * 16 + fl];
            if (q < rem) addbf(a0, va);
        }
    }
    {   // list 1
        int e = off1[n], e_ = off1[n + 1];
        for (; e + 8 <= e_; e += 8) {
            int ia = csr1[e + q], ib = csr1[e + 4 + q];
            uint2 va = G1[(size_t)ia * 16 + fl];
            uint2 vb = G1[(size_t)ib * 16 + fl];
            addbf(a1, va); addbf(a1, vb);
        }
        if (e + 4 <= e_) {
            int ia = csr1[e + q];
            addbf(a1, G1[(size_t)ia * 16 + fl]);
            e += 4;
        }
        int rem = e_ - e;
        if (rem > 0) {
            int ia = csr1[e + (q < rem ? q : rem - 1)];
            uint2 va = G1[(size_t)ia * 16 + fl];
            if (q < rem) addbf(a1, va);
        }
    }
    float d0 = dinv0[n], d1 = dinv1[n];
    #pragma unroll
    for (int k = 0; k < 4; ++k) {            // fold edge slots
        a0[k] += __shfl_xor(a0[k], 16, 64);
        a0[k] += __shfl_xor(a0[k], 32, 64);
        a1[k] += __shfl_xor(a1[k], 16, 64);
        a1[k] += __shfl_xor(a1[k], 32, 64);
        a0[k] *= d0;
        a1[k] *= d1;
    }
    if (q == 0) {
        *(float4*)&l0[w][fl * 4] = make_float4(a0[0], a0[1], a0[2], a0[3]);
        *(float4*)&l1[w][fl * 4] = make_float4(a1[0], a1[1], a1[2], a1[3]);
        *(float4*)&t0[(size_t)n * HID + fl * 4] = make_float4(a0[0], a0[1], a0[2], a0[3]);
    }
    int h = lane;                            // matvec (wave-local LDS)
    const float* W0 = W_conv;
    const float* W1 = W_conv + HID * HID;
    float m0 = b_conv[h];
    float m1 = b_conv[HID + h];
    #pragma unroll 8
    for (int k = 0; k < HID; ++k) {
        m0 = fmaf(l0[w][k], W0[k * HID + h], m0);
        m1 = fmaf(l1[w][k], W1[k * HID + h], m1);
    }
    s1g[(size_t)n * HID + h] = f2bf(fmaxf(m0, m1) * d0);
}

// ------- layer 2: 4-edge-wide gather(s1g, csr0) + matvec + max + LN + gelu + W3 -------
__global__ void layer2(const float* __restrict__ t0, const ushort* __restrict__ s1g,
                       const int* __restrict__ off0, const int* __restrict__ csr0,
                       const float* __restrict__ dinv0,
                       const float* __restrict__ W_conv, const float* __restrict__ b_conv,
                       const float* __restrict__ W3, const float* __restrict__ b3,
                       float* __restrict__ out, int N) {
    __shared__ float l2[4][HID], l3[4][HID], gs[4][HID];
    int w = threadIdx.x >> 6, lane = threadIdx.x & 63;
    int n = blockIdx.x * 4 + w;
    if (n >= N) return;
    int q = lane >> 4, fl = lane & 15;
    const uint2* S = (const uint2*)s1g;
    float a[4] = {0, 0, 0, 0};
    if (q == 0) addbf(a, S[(size_t)n * 16 + fl]);   // self
    {
        int e = off0[n], e_ = off0[n + 1];
        for (; e + 8 <= e_; e += 8) {
            int ia = csr0[e + q], ib = csr0[e + 4 + q];
            uint2 va = S[(size_t)ia * 16 + fl];
            uint2 vb = S[(size_t)ib * 16 + fl];
            addbf(a, va); addbf(a, vb);
        }
        if (e + 4 <= e_) {
            int ia = csr0[e + q];
            addbf(a, S[(size_t)ia * 16 + fl]);
            e += 4;
        }
        int rem = e_ - e;
        if (rem > 0) {
            int ia = csr0[e + (q < rem ? q : rem - 1)];
            uint2 va = S[(size_t)ia * 16 + fl];
            if (q < rem) addbf(a, va);
        }
    }
    float d0 = dinv0[n];
    #pragma unroll
    for (int k = 0; k < 4; ++k) {
        a[k] += __shfl_xor(a[k], 16, 64);
        a[k] += __shfl_xor(a[k], 32, 64);
        a[k] *= d0;
    }
    if (q == 0)
        *(float4*)&l3[w][fl * 4] = make_float4(a[0], a[1], a[2], a[3]);
    int h = lane;
    l2[w][h] = t0[(size_t)n * HID + h];
    const float* W2  = W_conv + 2 * HID * HID;
    const float* W3c = W_conv + 3 * HID * HID;
    float m2 = b_conv[2 * HID + h];
    float m3 = b_conv[3 * HID + h];
    #pragma unroll 8
    for (int k = 0; k < HID; ++k) {
        m2 = fmaf(l2[w][k], W2[k * HID + h], m2);
        m3 = fmaf(l3[w][k], W3c[k * HID + h], m3);
    }
    float s2 = fmaxf(m2, m3);
    float sum = s2;
    #pragma unroll
    for (int off = 32; off; off >>= 1) sum += __shfl_xor(sum, off, 64);
    float mu = sum * (1.0f / 64.0f);
    float dv = s2 - mu;
    float v = dv * dv;
    #pragma unroll
    for (int off = 32; off; off >>= 1) v += __shfl_xor(v, off, 64);
    float xn = dv * rsqrtf(v * (1.0f / 64.0f) + 1e-5f);
    float g = 0.5f * xn * (1.0f + erff(xn * 0.70710678118654752f));
    gs[w][h] = g;
    if (h < 8) {
        float acc = b3[h];
        #pragma unroll 8
        for (int k = 0; k < HID; ++k)
            acc = fmaf(gs[w][k], W3[k * 8 + h], acc);
        out[(size_t)n * 8 + h] = acc;
    }
}

extern "C" void kernel_launch(void* const* d_in, const int* in_sizes, int n_in,
                              void* d_out, int out_size, void* d_ws, size_t ws_size,
                              hipStream_t stream) {
    const float* x          = (const float*)d_in[0];
    const int*   node_types = (const int*)d_in[1];
    const int*   e0         = (const int*)d_in[2];   // (2,E): [0..E)=src, [E..2E)=dst
    const int*   e1         = (const int*)d_in[3];
    const float* W_in       = (const float*)d_in[4];
    const float* b_in       = (const float*)d_in[5];
    const float* W_conv     = (const float*)d_in[6];
    const float* b_conv     = (const float*)d_in[7];
    const float* W3         = (const float*)d_in[12];
    const float* b3         = (const float*)d_in[13];
    float* out = (float*)d_out;

    int N = in_sizes[1];
    int F = in_sizes[0] / N;    // 128
    int E = in_sizes[2] / 2;    // 1.6M
    int BW = (N + RB - 1) / RB; // 782 (< 1024 for packing)
    unsigned M = (unsigned)(0x100000000ULL / (unsigned long long)BW) + 1u;  // magic div

    // workspace layout (4-byte units); arena aliases t0
    int*   bcnt  = (int*)d_ws;                 // 2*RB
    int*   bbase = bcnt + 2 * RB;              // 2*(RB+1)
    int*   bcur  = bbase + 2 * (RB + 1);       // 2*RB, pad
    int*   off0  = bcur + 2 * RB + 6;          // N+1
    int*   off1  = off0 + (N + 1);             // N+1
    float* dinv0 = (float*)(off1 + (N + 1));   // N
    float* dinv1 = dinv0 + N;                  // N
    int*   csr0  = (int*)(dinv1 + N);          // E
    int*   csr1  = csr0 + E;                   // E
    ushort* g0   = (ushort*)(csr1 + E);        // 64N bf16
    ushort* g1   = g0 + (size_t)HID * N;       // 64N bf16
    float* t0    = (float*)(g1 + (size_t)HID * N);  // 64N fp32 (aliases arena)
    ushort* s1g  = (ushort*)(t0 + (size_t)HID * N); // 64N bf16
    unsigned* arena = (unsigned*)t0;           // 2 lists × E u32 (dead before layer1)

    (void)hipMemsetAsync(bcnt, 0, 2 * RB * sizeof(int), stream);
    histA<<<1024, 256, 0, stream>>>(e0 + E, e1 + E, E, M, bcnt);
    scanA<<<1, 256, 0, stream>>>(bcnt, bbase, bcur, E, off0, off1, N);
    partB<<<256, 256, 0, stream>>>(e0, e1, E, BW, M, bcur, arena);
    buildC<<<2 * RB, 1024, 0, stream>>>(arena, bbase, E, N, BW,
                                        csr0, csr1, off0, off1, dinv0, dinv1);
    input_proj<<<(N + 3) / 4, 256, 0, stream>>>(x, node_types, W_in, b_in,
                                                dinv0, dinv1, g0, g1, N, F);
    layer1<<<(N + 3) / 4, 256, 0, stream>>>(g0, g1, off0, csr0, dinv0, off1, csr1, dinv1,
                                            W_conv, b_conv, t0, s1g, N);
    layer2<<<(N + 3) / 4, 256, 0, stream>>>(t0, s1g, off0, csr0, dinv0,
                                            W_conv, b_conv, W3, b3, out, N);
}

// Round 10
// 518.255 us; speedup vs baseline: 3.2349x; 1.0483x over previous
//
#include <hip/hip_runtime.h>
#include <hip/hip_bf16.h>
#include <math.h>

// HGNN forward, MI355X — round 10: unified gather array (gh, unscaled bf16),
// padded CSR (segments multiple of 8, pad index = zero row N), software-
// pipelined index loads, LDS-staged bf16 weights, bf16 agg0, 512-thr blocks.
// attn == softmax over size-1 axis == 1.0 exactly, so W1/b1/W2/b2 are unused.

#define HID   64
#define RB    128
#define CHUNK 4096

__device__ __forceinline__ float bflo(unsigned u) { return __int_as_float((int)(u << 16)); }
__device__ __forceinline__ float bfhi(unsigned u) { return __int_as_float((int)(u & 0xFFFF0000u)); }
__device__ __forceinline__ float bf2f(ushort v) { return __int_as_float((int)(((unsigned)v) << 16)); }
__device__ __forceinline__ ushort f2bf(float f) {
    unsigned u = __float_as_uint(f);
    unsigned r = u + 0x7FFFu + ((u >> 16) & 1u);
    return (ushort)(r >> 16);
}

// ---------------- tiny init: zero rows + dinv sentinels ----------------
__global__ void zeroRow(unsigned* __restrict__ ghz, unsigned* __restrict__ s1z,
                        float* __restrict__ dinv0, float* __restrict__ dinv1, int N) {
    int tid = threadIdx.x;
    if (tid < 32) { ghz[tid] = 0u; s1z[tid] = 0u; }
    if (tid == 0) { dinv0[N] = 0.0f; dinv1[N] = 0.0f; }
}

// ---------------- bucket histogram ----------------
__global__ void histA(const int* __restrict__ dst0, const int* __restrict__ dst1,
                      int E, unsigned M, int* __restrict__ bcnt) {
    __shared__ int h[2 * RB];
    for (int i = threadIdx.x; i < 2 * RB; i += blockDim.x) h[i] = 0;
    __syncthreads();
    int stride = gridDim.x * blockDim.x;
    for (int i = blockIdx.x * blockDim.x + threadIdx.x; i < E; i += stride) {
        atomicAdd(&h[__umulhi((unsigned)dst0[i], M)], 1);
        atomicAdd(&h[RB + __umulhi((unsigned)dst1[i], M)], 1);
    }
    __syncthreads();
    for (int i = threadIdx.x; i < 2 * RB; i += blockDim.x)
        if (h[i]) atomicAdd(&bcnt[i], h[i]);
}

// ---------------- bucket scan ----------------
__global__ void scanA(const int* __restrict__ bcnt, int* __restrict__ bbase,
                      int* __restrict__ bcur) {
    __shared__ int t[2 * RB];
    int tid = threadIdx.x;
    int orig = bcnt[tid];
    t[tid] = orig;
    __syncthreads();
    int list = tid >> 7, r = tid & (RB - 1);
    for (int o = 1; o < RB; o <<= 1) {
        int u = (r >= o) ? t[tid - o] : 0;
        __syncthreads();
        t[tid] += u;
        __syncthreads();
    }
    int incl = t[tid];
    int excl = incl - orig;
    bbase[list * (RB + 1) + r] = excl;
    bcur[tid] = excl;
    if (r == RB - 1) bbase[list * (RB + 1) + RB] = incl;   // == E
}

// ------- partition: chunked counting sort -> bucket-ordered packed arena -------
__global__ void __launch_bounds__(256) partB(const int* __restrict__ e0,
                                             const int* __restrict__ e1,
                                             int E, int BW, unsigned M,
                                             int* __restrict__ bcur_all,
                                             unsigned* __restrict__ arena_all) {
    __shared__ int hist[RB], scn[RB], lbase[RB], cur[RB], gbase[RB];
    __shared__ uint2 buf[CHUNK];
    int half = gridDim.x >> 1;
    int list = (blockIdx.x >= half) ? 1 : 0;
    const int* src = list ? e1 : e0;
    const int* dst = src + E;
    int* bcur = bcur_all + list * RB;
    unsigned* arena = arena_all + (size_t)list * E;
    int blk = blockIdx.x - list * half;
    int tid = threadIdx.x;

    for (int c0 = blk * CHUNK; c0 < E; c0 += half * CHUNK) {
        int cn = min(CHUNK, E - c0);
        for (int i = tid; i < RB; i += 256) hist[i] = 0;
        __syncthreads();
        unsigned ls[16], ld[16];
        #pragma unroll
        for (int k = 0; k < 16; ++k) {
            int j = k * 256 + tid;
            ld[k] = 0xFFFFFFFFu; ls[k] = 0;
            if (j < cn) {
                ls[k] = (unsigned)src[c0 + j];
                ld[k] = (unsigned)dst[c0 + j];
                atomicAdd(&hist[__umulhi(ld[k], M)], 1);
            }
        }
        __syncthreads();
        if (tid < RB) scn[tid] = hist[tid];
        __syncthreads();
        for (int o = 1; o < RB; o <<= 1) {
            int u = (tid < RB && tid >= o) ? scn[tid - o] : 0;
            __syncthreads();
            if (tid < RB) scn[tid] += u;
            __syncthreads();
        }
        if (tid < RB) {
            int ex = scn[tid] - hist[tid];
            lbase[tid] = ex;
            cur[tid]   = ex;
            gbase[tid] = hist[tid] ? atomicAdd(&bcur[tid], hist[tid]) : 0;
        }
        __syncthreads();
        #pragma unroll
        for (int k = 0; k < 16; ++k) {
            if (ld[k] != 0xFFFFFFFFu) {
                int b = __umulhi(ld[k], M);
                int slot = atomicAdd(&cur[b], 1);
                buf[slot] = make_uint2(ls[k], ld[k]);
            }
        }
        __syncthreads();
        for (int i = tid; i < cn; i += 256) {
            uint2 p = buf[i];
            int b = __umulhi(p.y, M);
            arena[gbase[b] + (i - lbase[b])] = (p.x << 10) | (p.y - (unsigned)(b * BW));
        }
        __syncthreads();
    }
}

// ------- per-bucket padded CSR build: off-word = base | (niter<<25) -------
__global__ void __launch_bounds__(1024) buildC(const unsigned* __restrict__ arena_all,
                                               const int* __restrict__ bbase,
                                               int E, int N, int BW,
                                               int* __restrict__ csr0p, int* __restrict__ csr1p,
                                               unsigned* __restrict__ offp0, unsigned* __restrict__ offp1,
                                               float* __restrict__ dinv0, float* __restrict__ dinv1) {
    __shared__ int degl[800], scn[800], cur[800];
    int list = blockIdx.x >> 7, rb = blockIdx.x & (RB - 1);
    const unsigned* arena = arena_all + (size_t)list * E;
    int* csr = list ? csr1p : csr0p;
    unsigned* offp = list ? offp1 : offp0;
    float* dinv = list ? dinv1 : dinv0;
    int base = bbase[list * (RB + 1) + rb];
    int end  = bbase[list * (RB + 1) + rb + 1];
    int csrb = base + 8 * BW * rb;          // conservative padded-space base
    int nbase = rb * BW;
    int nn = min(BW, N - nbase);
    if (nn <= 0) return;
    int tid = threadIdx.x;
    for (int i = tid; i < nn; i += 1024) degl[i] = 0;
    __syncthreads();
    for (int j = base + tid; j < end; j += 1024)
        atomicAdd(&degl[arena[j] & 1023u], 1);
    __syncthreads();
    int d = (tid < nn) ? degl[tid] : 0;
    int dp = d ? ((d + 7) & ~7) : 0;        // pad to multiple of 8
    if (tid < nn) scn[tid] = dp;
    __syncthreads();
    for (int o = 1; o < nn; o <<= 1) {
        int u = (tid < nn && tid >= o) ? scn[tid - o] : 0;
        __syncthreads();
        if (tid < nn) scn[tid] += u;
        __syncthreads();
    }
    if (tid < nn) {
        int ex = scn[tid] - dp;             // padded exclusive
        cur[tid] = ex;
        offp[nbase + tid] = (unsigned)(csrb + ex) | ((unsigned)(dp >> 3) << 25);
        dinv[nbase + tid] = rsqrtf((float)(d + 1));
        for (int j = ex + d; j < ex + dp; ++j) csr[csrb + j] = N;   // pads -> zero row
    }
    __syncthreads();
    for (int j = base + tid; j < end; j += 1024) {
        unsigned p = arena[j];
        int loc = atomicAdd(&cur[p & 1023u], 1);
        csr[csrb + loc] = (int)(p >> 10);
    }
}

// ------ input projection: gh = bf16(x@W_in[t] + b_in[t]) (unscaled) ------
__global__ void input_proj(const float* __restrict__ x, const int* __restrict__ types,
                           const float* __restrict__ W_in, const float* __restrict__ b_in,
                           ushort* __restrict__ gh, int N, int F) {
    __shared__ float xs[4 * 128];
    int tid = threadIdx.x;
    int w = tid >> 6, h = tid & 63;
    int n0 = blockIdx.x * 4;
    for (int i = tid; i < 4 * F; i += 256) {
        int nn = n0 + i / F;
        xs[i] = (nn < N) ? x[(size_t)nn * F + (i % F)] : 0.0f;
    }
    __syncthreads();
    int n = n0 + w;
    if (n >= N) return;
    int t = types[n];
    const float* W = W_in + (size_t)t * F * HID;
    float acc = b_in[t * HID + h];
    const float* xr = xs + w * F;
    #pragma unroll 4
    for (int f = 0; f < F; ++f)
        acc = fmaf(xr[f], W[(size_t)f * HID + h], acc);
    gh[(size_t)n * HID + h] = f2bf(acc);
}

// weighted gather over one padded csr segment; 4 edges/instr, idx pipelined
__device__ __forceinline__ void gather_w(const uint2* __restrict__ GH,
                                         const float* __restrict__ dv,
                                         const int* __restrict__ csr,
                                         unsigned wword, int q, int fl, float a[4]) {
    int base = (int)(wword & 0x1FFFFFFu);
    int it = (int)(wword >> 25);
    if (it == 0) return;
    const int* cp = csr + base;
    int ia = cp[q], ib = cp[4 + q];
    while (true) {
        uint2 va = GH[(size_t)ia * 16 + fl];
        uint2 vb = GH[(size_t)ib * 16 + fl];
        float wa = dv[ia], wb = dv[ib];
        --it; cp += 8;
        int na = 0, nb = 0;
        if (it > 0) { na = cp[q]; nb = cp[4 + q]; }   // wave-uniform branch
        a[0] = fmaf(bflo(va.x), wa, a[0]);
        a[1] = fmaf(bfhi(va.x), wa, a[1]);
        a[2] = fmaf(bflo(va.y), wa, a[2]);
        a[3] = fmaf(bfhi(va.y), wa, a[3]);
        a[0] = fmaf(bflo(vb.x), wb, a[0]);
        a[1] = fmaf(bfhi(vb.x), wb, a[1]);
        a[2] = fmaf(bflo(vb.y), wb, a[2]);
        a[3] = fmaf(bfhi(vb.y), wb, a[3]);
        if (it == 0) break;
        ia = na; ib = nb;
    }
}

// unweighted gather (source pre-scaled)
__device__ __forceinline__ void gather_u(const uint2* __restrict__ GH,
                                         const int* __restrict__ csr,
                                         unsigned wword, int q, int fl, float a[4]) {
    int base = (int)(wword & 0x1FFFFFFu);
    int it = (int)(wword >> 25);
    if (it == 0) return;
    const int* cp = csr + base;
    int ia = cp[q], ib = cp[4 + q];
    while (true) {
        uint2 va = GH[(size_t)ia * 16 + fl];
        uint2 vb = GH[(size_t)ib * 16 + fl];
        --it; cp += 8;
        int na = 0, nb = 0;
        if (it > 0) { na = cp[q]; nb = cp[4 + q]; }
        a[0] += bflo(va.x) + bflo(vb.x);
        a[1] += bfhi(va.x) + bfhi(vb.x);
        a[2] += bflo(va.y) + bflo(vb.y);
        a[3] += bfhi(va.y) + bfhi(vb.y);
        if (it == 0) break;
        ia = na; ib = nb;
    }
}

// ------- layer 1: two weighted gathers over gh + W0/W1 matvec + max -------
__global__ void __launch_bounds__(512) gatherL1(
        const ushort* __restrict__ gh,
        const unsigned* __restrict__ offp0, const int* __restrict__ csr0p,
        const float* __restrict__ dinv0,
        const unsigned* __restrict__ offp1, const int* __restrict__ csr1p,
        const float* __restrict__ dinv1,
        const float* __restrict__ W_conv, const float* __restrict__ b_conv,
        unsigned* __restrict__ a0g, ushort* __restrict__ s1g, int N) {
    __shared__ ushort Wb[2 * HID * HID];       // 16 KB bf16 W0,W1
    __shared__ float l0[8][HID], l1[8][HID];
    int tid = threadIdx.x;
    for (int i = tid; i < 2 * HID * HID; i += 512) Wb[i] = f2bf(W_conv[i]);
    __syncthreads();
    int w = tid >> 6, lane = tid & 63;
    int q = lane >> 4, fl = lane & 15;
    int n = blockIdx.x * 8 + w;
    if (n >= N) return;
    const uint2* GH = (const uint2*)gh;
    float d0 = dinv0[n], d1 = dinv1[n];
    float a0[4] = {0, 0, 0, 0}, a1[4] = {0, 0, 0, 0};
    if (q == 0) {                              // self terms (weight dinv[n])
        uint2 sv = GH[(size_t)n * 16 + fl];
        a0[0] = bflo(sv.x) * d0; a0[1] = bfhi(sv.x) * d0;
        a0[2] = bflo(sv.y) * d0; a0[3] = bfhi(sv.y) * d0;
        a1[0] = bflo(sv.x) * d1; a1[1] = bfhi(sv.x) * d1;
        a1[2] = bflo(sv.y) * d1; a1[3] = bfhi(sv.y) * d1;
    }
    gather_w(GH, dinv0, csr0p, offp0[n], q, fl, a0);
    gather_w(GH, dinv1, csr1p, offp1[n], q, fl, a1);
    #pragma unroll
    for (int k = 0; k < 4; ++k) {
        a0[k] += __shfl_xor(a0[k], 16, 64);
        a0[k] += __shfl_xor(a0[k], 32, 64);
        a1[k] += __shfl_xor(a1[k], 16, 64);
        a1[k] += __shfl_xor(a1[k], 32, 64);
        a0[k] *= d0;
        a1[k] *= d1;
    }
    if (q == 0) {
        *(float4*)&l0[w][fl * 4] = make_float4(a0[0], a0[1], a0[2], a0[3]);
        *(float4*)&l1[w][fl * 4] = make_float4(a1[0], a1[1], a1[2], a1[3]);
        uint2 pk;
        pk.x = (unsigned)f2bf(a0[0]) | ((unsigned)f2bf(a0[1]) << 16);
        pk.y = (unsigned)f2bf(a0[2]) | ((unsigned)f2bf(a0[3]) << 16);
        ((uint2*)a0g)[(size_t)n * 16 + fl] = pk;      // agg0 bf16 for layer 2
    }
    int h = lane;
    float m0 = b_conv[h];
    float m1 = b_conv[HID + h];
    #pragma unroll 8
    for (int k = 0; k < HID; ++k) {
        m0 = fmaf(l0[w][k], bf2f(Wb[k * HID + h]), m0);
        m1 = fmaf(l1[w][k], bf2f(Wb[HID * HID + k * HID + h]), m1);
    }
    s1g[(size_t)n * HID + h] = f2bf(fmaxf(m0, m1) * d0);
}

// ------- layer 2: unweighted gather(s1g) + W2/W3c matvec + max + LN + gelu + W3 -------
__global__ void __launch_bounds__(512) gatherL2(
        const unsigned* __restrict__ a0g, const ushort* __restrict__ s1g,
        const unsigned* __restrict__ offp0, const int* __restrict__ csr0p,
        const float* __restrict__ dinv0,
        const float* __restrict__ W_conv, const float* __restrict__ b_conv,
        const float* __restrict__ W3, const float* __restrict__ b3,
        float* __restrict__ out, int N) {
    __shared__ ushort Wb[2 * HID * HID];       // 16 KB bf16 W2,W3c
    __shared__ float W3s[HID * 8];             // 2 KB
    __shared__ float l2[8][HID], l3[8][HID], gs[8][HID];
    int tid = threadIdx.x;
    for (int i = tid; i < 2 * HID * HID; i += 512) Wb[i] = f2bf(W_conv[2 * HID * HID + i]);
    if (tid < HID * 8) W3s[tid] = W3[tid];
    __syncthreads();
    int w = tid >> 6, lane = tid & 63;
    int q = lane >> 4, fl = lane & 15;
    int n = blockIdx.x * 8 + w;
    if (n >= N) return;
    const uint2* S = (const uint2*)s1g;
    float d0 = dinv0[n];
    float a[4] = {0, 0, 0, 0};
    if (q == 0) {
        uint2 sv = S[(size_t)n * 16 + fl];
        a[0] = bflo(sv.x); a[1] = bfhi(sv.x);
        a[2] = bflo(sv.y); a[3] = bfhi(sv.y);
        uint2 av = ((const uint2*)a0g)[(size_t)n * 16 + fl];     // stage agg0 row
        *(float4*)&l2[w][fl * 4] = make_float4(bflo(av.x), bfhi(av.x), bflo(av.y), bfhi(av.y));
    }
    gather_u(S, csr0p, offp0[n], q, fl, a);
    #pragma unroll
    for (int k = 0; k < 4; ++k) {
        a[k] += __shfl_xor(a[k], 16, 64);
        a[k] += __shfl_xor(a[k], 32, 64);
        a[k] *= d0;
    }
    if (q == 0)
        *(float4*)&l3[w][fl * 4] = make_float4(a[0], a[1], a[2], a[3]);
    int h = lane;
    float m2 = b_conv[2 * HID + h];
    float m3 = b_conv[3 * HID + h];
    #pragma unroll 8
    for (int k = 0; k < HID; ++k) {
        m2 = fmaf(l2[w][k], bf2f(Wb[k * HID + h]), m2);
        m3 = fmaf(l3[w][k], bf2f(Wb[HID * HID + k * HID + h]), m3);
    }
    float s2 = fmaxf(m2, m3);
    float sum = s2;
    #pragma unroll
    for (int off = 32; off; off >>= 1) sum += __shfl_xor(sum, off, 64);
    float mu = sum * (1.0f / 64.0f);
    float dv = s2 - mu;
    float v = dv * dv;
    #pragma unroll
    for (int off = 32; off; off >>= 1) v += __shfl_xor(v, off, 64);
    float xn = dv * rsqrtf(v * (1.0f / 64.0f) + 1e-5f);
    float g = 0.5f * xn * (1.0f + erff(xn * 0.70710678118654752f));
    gs[w][h] = g;
    if (h < 8) {
        float acc = b3[h];
        #pragma unroll 8
        for (int k = 0; k < HID; ++k)
            acc = fmaf(gs[w][k], W3s[k * 8 + h], acc);
        out[(size_t)n * 8 + h] = acc;
    }
}

extern "C" void kernel_launch(void* const* d_in, const int* in_sizes, int n_in,
                              void* d_out, int out_size, void* d_ws, size_t ws_size,
                              hipStream_t stream) {
    const float* x          = (const float*)d_in[0];
    const int*   node_types = (const int*)d_in[1];
    const int*   e0         = (const int*)d_in[2];
    const int*   e1         = (const int*)d_in[3];
    const float* W_in       = (const float*)d_in[4];
    const float* b_in       = (const float*)d_in[5];
    const float* W_conv     = (const float*)d_in[6];
    const float* b_conv     = (const float*)d_in[7];
    const float* W3         = (const float*)d_in[12];
    const float* b3         = (const float*)d_in[13];
    float* out = (float*)d_out;

    int N = in_sizes[1];
    int F = in_sizes[0] / N;        // 128
    int E = in_sizes[2] / 2;        // 1.6M
    int BW = (N + RB - 1) / RB;     // 782
    unsigned M = (unsigned)(0x100000000ULL / (unsigned long long)BW) + 1u;
    size_t EP = (size_t)E + 8 * (size_t)BW * RB + 64;   // padded csr capacity

    // workspace layout (u32 units)
    unsigned* ws32 = (unsigned*)d_ws;
    int*      bcnt  = (int*)ws32;                        // 2*RB
    int*      bbase = bcnt + 2 * RB;                     // 2*(RB+1)
    int*      bcur  = bbase + 2 * (RB + 1);              // 2*RB (+6 pad)
    unsigned* offp0 = (unsigned*)(bcur + 2 * RB + 6);    // N+1
    unsigned* offp1 = offp0 + (N + 1);                   // N+1
    float*    dinv0 = (float*)(offp1 + (N + 1));         // N+1
    float*    dinv1 = dinv0 + (N + 1);                   // N+1
    int*      csr0p = (int*)(dinv1 + (N + 1));           // EP
    int*      csr1p = csr0p + EP;                        // EP
    ushort*   gh    = (ushort*)(csr1p + EP);             // (N+1)*64 bf16
    ushort*   s1g   = gh + (size_t)(N + 1) * HID;        // (N+1)*64 bf16
    unsigned* a0g   = (unsigned*)(s1g + (size_t)(N + 1) * HID);  // N*32 u32
    unsigned* arena = a0g;                               // 2E u32, dead before gatherL1

    (void)hipMemsetAsync(bcnt, 0, 2 * RB * sizeof(int), stream);
    zeroRow<<<1, 64, 0, stream>>>((unsigned*)(gh + (size_t)N * HID),
                                  (unsigned*)(s1g + (size_t)N * HID), dinv0, dinv1, N);
    histA<<<1024, 256, 0, stream>>>(e0 + E, e1 + E, E, M, bcnt);
    scanA<<<1, 256, 0, stream>>>(bcnt, bbase, bcur);
    partB<<<256, 256, 0, stream>>>(e0, e1, E, BW, M, bcur, arena);
    buildC<<<2 * RB, 1024, 0, stream>>>(arena, bbase, E, N, BW,
                                        csr0p, csr1p, offp0, offp1, dinv0, dinv1);
    input_proj<<<(N + 3) / 4, 256, 0, stream>>>(x, node_types, W_in, b_in, gh, N, F);
    gatherL1<<<(N + 7) / 8, 512, 0, stream>>>(gh, offp0, csr0p, dinv0, offp1, csr1p, dinv1,
                                              W_conv, b_conv, a0g, s1g, N);
    gatherL2<<<(N + 7) / 8, 512, 0, stream>>>(a0g, s1g, offp0, csr0p, dinv0,
                                              W_conv, b_conv, W3, b3, out, N);
}